// Round 2
// baseline (2770.209 us; speedup 1.0000x reference)
//
#include <hip/hip_runtime.h>
#include <hip/hip_bf16.h>
#include <cstdint>

typedef _Float16 half2v __attribute__((ext_vector_type(2)));

#define EPB   32        // entities per bucket
#define MAXNB 1024      // max buckets supported by LDS histogram (NUMENT <= 32768)
#define FPB   4096      // facts per bin-block
#define FPT   16        // facts per thread (256 threads/block)

// ---------------------------------------------------------------------------
// Kernel 1: RWB[r][n] = dot(rel_features[r,:], W[n,:]) + b[n]   (fp16, [R][128])
// Row-major: gather reads row r as 256 contiguous bytes (L2-resident table).
// ---------------------------------------------------------------------------
__global__ void rwb_row_kernel(const float* __restrict__ rel, const float* __restrict__ W,
                               const float* __restrict__ b, _Float16* __restrict__ rwb,
                               int R) {
    const int k = blockIdx.x;        // relation index
    const int n = threadIdx.x;       // output feature (0..127)
    __shared__ float relk[128];
    relk[n] = rel[(size_t)k * 128 + n];
    __syncthreads();
    const float4* w4 = reinterpret_cast<const float4*>(W + (size_t)n * 128);
    const float4* r4 = reinterpret_cast<const float4*>(relk);
    float acc = 0.f;
#pragma unroll
    for (int i = 0; i < 32; ++i) {
        float4 a = r4[i], w = w4[i];
        acc += a.x * w.x + a.y * w.y + a.z * w.z + a.w * w.w;
    }
    rwb[(size_t)k * 128 + n] = (_Float16)(acc + b[n]);
}

// ---------------------------------------------------------------------------
// Spill path for bucket-capacity overflow (statistically unreachable:
// per-bucket endpoints ~Poisson(8000), CAPB gives >10 sigma). Guard only.
// ---------------------------------------------------------------------------
__device__ __noinline__ void spill_add(float* __restrict__ out, const _Float16* __restrict__ rwb,
                                       int v, int r, float val) {
    float* o = out + (size_t)v * 128;
    const _Float16* rw = rwb + (size_t)r * 128;
    for (int n = 0; n < 128; ++n) unsafeAtomicAdd(o + n, val * (float)rw[n]);
}

// ---------------------------------------------------------------------------
// Kernel 2: bin endpoints into per-bucket lists.
// LDS histogram gives per-endpoint rank (ds_add_rtn, cheap); ONE global atomic
// per (bucket, block) reserves a contiguous range (244K atomics vs 4M).
// Stores land as ~16-entry contiguous runs per bucket -> minimal cross-XCD
// false sharing (round-1's 8x write amplification came from interleaved
// per-entity tails shared across XCD L2s).
// payload: x = (local_entity<<24) | rel, y = bits(val)
// ---------------------------------------------------------------------------
__global__ __launch_bounds__(256) void bin_kernel(
    const int* __restrict__ heads, const int* __restrict__ tails,
    const int* __restrict__ rels, const float* __restrict__ val,
    int* __restrict__ gcnt, uint2* __restrict__ slots,
    const _Float16* __restrict__ rwb, float* __restrict__ out,
    int E, int NB, int CAPB) {
    __shared__ int cnt[MAXNB];
    __shared__ int gbase[MAXNB];
    const int t = threadIdx.x;
    for (int k = t; k < NB; k += 256) cnt[k] = 0;
    __syncthreads();

    const int base = blockIdx.x * FPB;
    unsigned keyT[FPT], keyH[FPT], prT[FPT], prH[FPT];
    float fv[FPT];
#pragma unroll
    for (int u = 0; u < FPT; ++u) {
        const int i = base + u * 256 + t;
        prT[u] = 0xFFFFFFFFu;
        prH[u] = 0xFFFFFFFFu;
        if (i < E) {
            const int tl = tails[i], hd = heads[i], r = rels[i];
            fv[u] = val[i];
            const int bt = tl >> 5, bh = hd >> 5;            // EPB = 32
            keyT[u] = ((unsigned)(tl & 31) << 24) | (unsigned)r;
            keyH[u] = ((unsigned)(hd & 31) << 24) | (unsigned)r;
            const int rt = atomicAdd(&cnt[bt], 1);           // LDS rank
            const int rh = atomicAdd(&cnt[bh], 1);
            prT[u] = ((unsigned)bt << 16) | (unsigned)rt;    // rank < 8192 fits
            prH[u] = ((unsigned)bh << 16) | (unsigned)rh;
        }
    }
    __syncthreads();
    for (int k = t; k < NB; k += 256) {
        const int c = cnt[k];
        gbase[k] = c ? atomicAdd(&gcnt[k], c) : 0;           // 1 atomic / bucket / block
    }
    __syncthreads();
#pragma unroll
    for (int u = 0; u < FPT; ++u) {
        if (prT[u] != 0xFFFFFFFFu) {
            {
                const int b = (int)(prT[u] >> 16);
                const int pos = gbase[b] + (int)(prT[u] & 0xFFFFu);
                uint2 pk; pk.x = keyT[u]; pk.y = __float_as_uint(fv[u]);
                if (pos < CAPB) slots[(size_t)b * CAPB + pos] = pk;
                else spill_add(out, rwb, (b << 5) | (int)(keyT[u] >> 24),
                               (int)(keyT[u] & 0xFFFFFFu), fv[u]);
            }
            {
                const int b = (int)(prH[u] >> 16);
                const int pos = gbase[b] + (int)(prH[u] & 0xFFFFu);
                uint2 pk; pk.x = keyH[u]; pk.y = __float_as_uint(fv[u]);
                if (pos < CAPB) slots[(size_t)b * CAPB + pos] = pk;
                else spill_add(out, rwb, (b << 5) | (int)(keyH[u] >> 24),
                               (int)(keyH[u] & 0xFFFFFFu), fv[u]);
            }
        }
    }
}

// ---------------------------------------------------------------------------
// Kernel 3: one block per bucket. fp32 accumulate in LDS (ds_add_f32),
// bank-swizzled word index 2l + (l>>4) -> 2-way bank aliasing (free).
// RWB rows (512KB) are L2-resident. Replaces the dense-S GEMM entirely.
// ---------------------------------------------------------------------------
__global__ __launch_bounds__(512) void gather_kernel(
    const uint2* __restrict__ slots, const int* __restrict__ gcnt,
    const _Float16* __restrict__ rwb, float* __restrict__ out,
    int NUMENT, int CAPB) {
    __shared__ float acc[EPB * 132];     // 132-word rows: swizzle range 0..130
    const int t = threadIdx.x;
    const int b = blockIdx.x;
    for (int k = t; k < EPB * 132; k += 512) acc[k] = 0.f;
    __syncthreads();

    int deg = gcnt[b];
    if (deg > CAPB) deg = CAPB;
    const uint2* sl = slots + (size_t)b * CAPB;
    const unsigned* rwb32 = reinterpret_cast<const unsigned*>(rwb);
    const int wv = t >> 6, lane = t & 63;
    const int s = lane >> 4;                       // swizzle shift 0..3
    const int j0 = (deg * wv) >> 3;                // contiguous per-wave range
    const int j1 = (deg * (wv + 1)) >> 3;

    int j = j0;
    for (; j + 8 <= j1; j += 8) {
        uint2 e[8];
#pragma unroll
        for (int u = 0; u < 8; ++u) e[u] = sl[j + u];      // wave-uniform 8B loads
#pragma unroll
        for (int u = 0; u < 8; ++u) {
            const int rel = (int)(e[u].x & 0xFFFFFFu);
            const int le  = (int)(e[u].x >> 24);
            const float w = __uint_as_float(e[u].y);
            const unsigned rw = rwb32[(size_t)rel * 64 + lane];   // 4B/lane, 256B row
            const half2v h = __builtin_bit_cast(half2v, rw);
            float* p = &acc[le * 132 + 2 * lane + s];
            atomicAdd(p,     w * (float)h[0]);             // ds_add_f32, no return
            atomicAdd(p + 1, w * (float)h[1]);
        }
    }
    for (; j < j1; ++j) {
        const uint2 e = sl[j];
        const int rel = (int)(e.x & 0xFFFFFFu);
        const int le  = (int)(e.x >> 24);
        const float w = __uint_as_float(e.y);
        const unsigned rw = rwb32[(size_t)rel * 64 + lane];
        const half2v h = __builtin_bit_cast(half2v, rw);
        float* p = &acc[le * 132 + 2 * lane + s];
        atomicAdd(p,     w * (float)h[0]);
        atomicAdd(p + 1, w * (float)h[1]);
    }
    __syncthreads();

    // readout: 32 entities x 64 lane-pairs = 2048 pairs over 512 threads
#pragma unroll
    for (int k = 0; k < 4; ++k) {
        const int p  = t + k * 512;
        const int le = p >> 6, l = p & 63;
        const int vent = b * EPB + le;
        if (vent < NUMENT) {
            const int ss = l >> 4;
            const float a0 = acc[le * 132 + 2 * l + ss];
            const float a1 = acc[le * 132 + 2 * l + ss + 1];
            float* op = out + (size_t)vent * 128 + 2 * l;
            float2 sp = *reinterpret_cast<const float2*>(op);  // spill contrib (normally 0)
            float2 o;
            o.x = fmaxf(a0 + sp.x, 0.f);
            o.y = fmaxf(a1 + sp.y, 0.f);
            *reinterpret_cast<float2*>(op) = o;
        }
    }
}

// ---------------------------------------------------------------------------
// Fallback path (ws too small / NUMENT too big): direct vector scatter.
// ---------------------------------------------------------------------------
__global__ void rwb_f32_kernel(const float* __restrict__ rel, const float* __restrict__ W,
                               const float* __restrict__ b, float* __restrict__ rwb, int R) {
    const int k = blockIdx.x;
    const int n = threadIdx.x;
    __shared__ float relk[128];
    relk[n] = rel[(size_t)k * 128 + n];
    __syncthreads();
    const float4* w4 = reinterpret_cast<const float4*>(W + (size_t)n * 128);
    const float4* r4 = reinterpret_cast<const float4*>(relk);
    float acc = 0.f;
#pragma unroll
    for (int i = 0; i < 32; ++i) {
        float4 a = r4[i], w = w4[i];
        acc += a.x * w.x + a.y * w.y + a.z * w.z + a.w * w.w;
    }
    rwb[(size_t)k * 128 + n] = acc + b[n];
}

__global__ void scatter_vec_kernel(const int* __restrict__ heads, const int* __restrict__ tails,
                                   const int* __restrict__ rels, const float* __restrict__ val,
                                   const float* __restrict__ rwb, float* __restrict__ out,
                                   long long nitems) {
    const long long i = (long long)blockIdx.x * blockDim.x + threadIdx.x;
    if (i >= nitems) return;
    const int e = (int)(i >> 5);
    const int c = (int)(i & 31) * 4;
    const float v = val[e];
    float4 rw = *reinterpret_cast<const float4*>(rwb + (size_t)rels[e] * 128 + c);
    float* pt = out + (size_t)tails[e] * 128 + c;
    float* ph = out + (size_t)heads[e] * 128 + c;
    unsafeAtomicAdd(pt + 0, v * rw.x); unsafeAtomicAdd(pt + 1, v * rw.y);
    unsafeAtomicAdd(pt + 2, v * rw.z); unsafeAtomicAdd(pt + 3, v * rw.w);
    unsafeAtomicAdd(ph + 0, v * rw.x); unsafeAtomicAdd(ph + 1, v * rw.y);
    unsafeAtomicAdd(ph + 2, v * rw.z); unsafeAtomicAdd(ph + 3, v * rw.w);
}

__global__ void relu_kernel(float* __restrict__ out, int n4) {
    const int i = blockIdx.x * blockDim.x + threadIdx.x;
    if (i >= n4) return;
    float4* p = reinterpret_cast<float4*>(out) + i;
    float4 v = *p;
    v.x = fmaxf(v.x, 0.f); v.y = fmaxf(v.y, 0.f);
    v.z = fmaxf(v.z, 0.f); v.w = fmaxf(v.w, 0.f);
    *p = v;
}

// ---------------------------------------------------------------------------
extern "C" void kernel_launch(void* const* d_in, const int* in_sizes, int n_in,
                              void* d_out, int out_size, void* d_ws, size_t ws_size,
                              hipStream_t stream) {
    // inputs: 0 local_entity [B*M] (shape only), 1 heads [E], 2 tails [E],
    //         3 rels [E], 4 val [E], 5 rel_features [R*D], 6 W [D*D], 7 b [D]
    const int* heads = (const int*)d_in[1];
    const int* tails = (const int*)d_in[2];
    const int* rels  = (const int*)d_in[3];
    const float* val  = (const float*)d_in[4];
    const float* relf = (const float*)d_in[5];
    const float* W    = (const float*)d_in[6];
    const float* b    = (const float*)d_in[7];
    float* out = (float*)d_out;

    const int NUMENT = in_sizes[0];          // 16000
    const int E      = in_sizes[1];          // 2,000,000
    const int D      = in_sizes[7];          // 128
    const int R      = in_sizes[5] / D;      // 2000

    const int NB = (NUMENT + EPB - 1) / EPB; // 500 buckets
    // expected endpoints/bucket = 2E*EPB/NUMENT (=8000); cap at mean+12.5%+512
    const long long mean = (2LL * E * EPB) / (NUMENT > 0 ? NUMENT : 1);
    int CAPB = (int)(mean + mean / 8 + 512);

    const size_t rwb_bytes = (size_t)R * D * sizeof(_Float16);          // 512 KB
    const size_t off_gcnt  = (rwb_bytes + 255) & ~(size_t)255;
    const size_t gcnt_b    = (size_t)NB * sizeof(int);
    const size_t off_slots = (off_gcnt + gcnt_b + 255) & ~(size_t)255;
    const size_t slots_b   = (size_t)NB * CAPB * sizeof(uint2);         // ~38 MB

    if (NB <= MAXNB && R < (1 << 24) &&
        ws_size >= off_slots + slots_b) {
        _Float16* rwb = (_Float16*)d_ws;
        int* gcnt     = (int*)((char*)d_ws + off_gcnt);
        uint2* slots  = (uint2*)((char*)d_ws + off_slots);

        hipMemsetAsync(gcnt, 0, gcnt_b, stream);
        hipMemsetAsync(out, 0, (size_t)out_size * sizeof(float), stream);
        rwb_row_kernel<<<R, 128, 0, stream>>>(relf, W, b, rwb, R);
        bin_kernel<<<(E + FPB - 1) / FPB, 256, 0, stream>>>(
            heads, tails, rels, val, gcnt, slots, rwb, out, E, NB, CAPB);
        gather_kernel<<<NB, 512, 0, stream>>>(slots, gcnt, rwb, out, NUMENT, CAPB);
    } else {
        // fallback: accumulate directly into out (slow but small-ws safe)
        float* rwb = (float*)d_ws;           // R*D fp32 (~1 MB)
        hipMemsetAsync(out, 0, (size_t)out_size * sizeof(float), stream);
        rwb_f32_kernel<<<R, 128, 0, stream>>>(relf, W, b, rwb, R);
        const long long items = (long long)E * 32;
        scatter_vec_kernel<<<(unsigned)((items + 255) / 256), 256, 0, stream>>>(
            heads, tails, rels, val, rwb, out, items);
        relu_kernel<<<(out_size / 4 + 255) / 256, 256, 0, stream>>>(out, out_size / 4);
    }
}

// Round 3
// 346.765 us; speedup vs baseline: 7.9887x; 7.9887x over previous
//
#include <hip/hip_runtime.h>
#include <hip/hip_bf16.h>
#include <cstdint>

typedef _Float16 half2v __attribute__((ext_vector_type(2)));

#define EPB   32        // entities per bucket
#define MAXNB 1024      // max buckets supported by LDS histogram (NUMENT <= 32768)
#define FPB   4096      // facts per bin-block
#define FPT   16        // facts per thread (256 threads/block)
#define GW    4         // gather waves per block (private LDS regions)

// ---------------------------------------------------------------------------
// Kernel 1: RWB[r][n] = dot(rel_features[r,:], W[n,:]) + b[n]   (fp16, [R][128])
// Row-major: gather reads row r as 256 contiguous bytes (L2-resident table).
// ---------------------------------------------------------------------------
__global__ void rwb_row_kernel(const float* __restrict__ rel, const float* __restrict__ W,
                               const float* __restrict__ b, _Float16* __restrict__ rwb,
                               int R) {
    const int k = blockIdx.x;        // relation index
    const int n = threadIdx.x;       // output feature (0..127)
    __shared__ float relk[128];
    relk[n] = rel[(size_t)k * 128 + n];
    __syncthreads();
    const float4* w4 = reinterpret_cast<const float4*>(W + (size_t)n * 128);
    const float4* r4 = reinterpret_cast<const float4*>(relk);
    float acc = 0.f;
#pragma unroll
    for (int i = 0; i < 32; ++i) {
        float4 a = r4[i], w = w4[i];
        acc += a.x * w.x + a.y * w.y + a.z * w.z + a.w * w.w;
    }
    rwb[(size_t)k * 128 + n] = (_Float16)(acc + b[n]);
}

// ---------------------------------------------------------------------------
// Spill path for bucket-capacity overflow (statistically unreachable:
// per-bucket endpoints ~Poisson(8000), CAPB gives >10 sigma). Guard only.
// ---------------------------------------------------------------------------
__device__ __noinline__ void spill_add(float* __restrict__ out, const _Float16* __restrict__ rwb,
                                       int v, int r, float val) {
    float* o = out + (size_t)v * 128;
    const _Float16* rw = rwb + (size_t)r * 128;
    for (int n = 0; n < 128; ++n) unsafeAtomicAdd(o + n, val * (float)rw[n]);
}

// ---------------------------------------------------------------------------
// Kernel 2: bin endpoints into per-bucket lists.  (UNCHANGED from round 2 —
// measured ~105us by subtraction; round-3 change isolates the gather fix.)
// payload: x = (local_entity<<24) | rel, y = bits(val)
// ---------------------------------------------------------------------------
__global__ __launch_bounds__(256) void bin_kernel(
    const int* __restrict__ heads, const int* __restrict__ tails,
    const int* __restrict__ rels, const float* __restrict__ val,
    int* __restrict__ gcnt, uint2* __restrict__ slots,
    const _Float16* __restrict__ rwb, float* __restrict__ out,
    int E, int NB, int CAPB) {
    __shared__ int cnt[MAXNB];
    __shared__ int gbase[MAXNB];
    const int t = threadIdx.x;
    for (int k = t; k < NB; k += 256) cnt[k] = 0;
    __syncthreads();

    const int base = blockIdx.x * FPB;
    unsigned keyT[FPT], keyH[FPT], prT[FPT], prH[FPT];
    float fv[FPT];
#pragma unroll
    for (int u = 0; u < FPT; ++u) {
        const int i = base + u * 256 + t;
        prT[u] = 0xFFFFFFFFu;
        prH[u] = 0xFFFFFFFFu;
        if (i < E) {
            const int tl = tails[i], hd = heads[i], r = rels[i];
            fv[u] = val[i];
            const int bt = tl >> 5, bh = hd >> 5;            // EPB = 32
            keyT[u] = ((unsigned)(tl & 31) << 24) | (unsigned)r;
            keyH[u] = ((unsigned)(hd & 31) << 24) | (unsigned)r;
            const int rt = atomicAdd(&cnt[bt], 1);           // LDS int rank (native)
            const int rh = atomicAdd(&cnt[bh], 1);
            prT[u] = ((unsigned)bt << 16) | (unsigned)rt;    // rank < 8192 fits
            prH[u] = ((unsigned)bh << 16) | (unsigned)rh;
        }
    }
    __syncthreads();
    for (int k = t; k < NB; k += 256) {
        const int c = cnt[k];
        gbase[k] = c ? atomicAdd(&gcnt[k], c) : 0;           // 1 atomic / bucket / block
    }
    __syncthreads();
#pragma unroll
    for (int u = 0; u < FPT; ++u) {
        if (prT[u] != 0xFFFFFFFFu) {
            {
                const int b = (int)(prT[u] >> 16);
                const int pos = gbase[b] + (int)(prT[u] & 0xFFFFu);
                uint2 pk; pk.x = keyT[u]; pk.y = __float_as_uint(fv[u]);
                if (pos < CAPB) slots[(size_t)b * CAPB + pos] = pk;
                else spill_add(out, rwb, (b << 5) | (int)(keyT[u] >> 24),
                               (int)(keyT[u] & 0xFFFFFFu), fv[u]);
            }
            {
                const int b = (int)(prH[u] >> 16);
                const int pos = gbase[b] + (int)(prH[u] & 0xFFFFu);
                uint2 pk; pk.x = keyH[u]; pk.y = __float_as_uint(fv[u]);
                if (pos < CAPB) slots[(size_t)b * CAPB + pos] = pk;
                else spill_add(out, rwb, (b << 5) | (int)(keyH[u] >> 24),
                               (int)(keyH[u] & 0xFFFFFFu), fv[u]);
            }
        }
    }
}

// ---------------------------------------------------------------------------
// Kernel 3: one block per bucket, 4 waves. Each wave scans a contiguous
// quarter of the bucket list and accumulates into its PRIVATE 16KB LDS region
// with plain (non-atomic) float2 RMW — lanes hit distinct addresses, waves hit
// distinct regions, so no atomicity needed. Round-2's atomicAdd(shared float)
// lowered to a ds CAS loop -> 2648us with all pipes idle. This removes it.
// Access pattern le*128 + 2*lane = 128 contiguous words/wave-op: conflict-free.
// ---------------------------------------------------------------------------
__global__ __launch_bounds__(256) void gather_kernel(
    const uint2* __restrict__ slots, const int* __restrict__ gcnt,
    const _Float16* __restrict__ rwb, float* __restrict__ out,
    int NUMENT, int CAPB) {
    __shared__ float acc[GW * EPB * 128];    // 64 KB -> 2 blocks/CU
    const int t = threadIdx.x;
    const int b = blockIdx.x;
    const int wv = t >> 6, lane = t & 63;
    float* myacc = &acc[wv * EPB * 128];

    // zero my wave's region (4096 words / 64 lanes = 64 per lane)
#pragma unroll
    for (int k = 0; k < 64; ++k) myacc[k * 64 + lane] = 0.f;

    int deg = gcnt[b];
    if (deg > CAPB) deg = CAPB;
    const uint2* sl = slots + (size_t)b * CAPB;
    const unsigned* rwb32 = reinterpret_cast<const unsigned*>(rwb);
    const int j0 = (deg * wv) >> 2;          // contiguous per-wave quarter
    const int j1 = (deg * (wv + 1)) >> 2;

    int j = j0;
    for (; j + 8 <= j1; j += 8) {
        uint2 e[8];
#pragma unroll
        for (int u = 0; u < 8; ++u) e[u] = sl[j + u];        // wave-uniform loads
        unsigned rw[8];
#pragma unroll
        for (int u = 0; u < 8; ++u)
            rw[u] = rwb32[(size_t)(e[u].x & 0xFFFFFFu) * 64 + lane]; // 256B row, L2
#pragma unroll
        for (int u = 0; u < 8; ++u) {
            const int le  = (int)(e[u].x >> 24);
            const float w = __uint_as_float(e[u].y);
            const half2v h = __builtin_bit_cast(half2v, rw[u]);
            float* p = &myacc[le * 128 + 2 * lane];
            float2 c = *reinterpret_cast<const float2*>(p);  // plain LDS RMW
            c.x += w * (float)h[0];
            c.y += w * (float)h[1];
            *reinterpret_cast<float2*>(p) = c;
        }
    }
    for (; j < j1; ++j) {
        const uint2 e = sl[j];
        const int le  = (int)(e.x >> 24);
        const float w = __uint_as_float(e.y);
        const unsigned rwv = rwb32[(size_t)(e.x & 0xFFFFFFu) * 64 + lane];
        const half2v h = __builtin_bit_cast(half2v, rwv);
        float* p = &myacc[le * 128 + 2 * lane];
        float2 c = *reinterpret_cast<const float2*>(p);
        c.x += w * (float)h[0];
        c.y += w * (float)h[1];
        *reinterpret_cast<float2*>(p) = c;
    }
    __syncthreads();

    // readout: sum 4 wave regions. 2048 float2 pairs over 256 threads = 8 each.
    const float2* a2 = reinterpret_cast<const float2*>(acc);
#pragma unroll
    for (int k = 0; k < 8; ++k) {
        const int p  = t + k * 256;          // pair index 0..2047
        const int le = p >> 6, l = p & 63;   // entity, feature-pair
        const int vent = b * EPB + le;
        if (vent < NUMENT) {
            const int idx = le * 64 + l;     // float2 index within a region
            float2 s0 = a2[idx];
            float2 s1 = a2[idx + 2048];
            float2 s2 = a2[idx + 4096];
            float2 s3 = a2[idx + 6144];
            float* op = out + (size_t)vent * 128 + 2 * l;
            float2 sp = *reinterpret_cast<const float2*>(op);   // spill (normally 0)
            float2 o;
            o.x = fmaxf(s0.x + s1.x + s2.x + s3.x + sp.x, 0.f);
            o.y = fmaxf(s0.y + s1.y + s2.y + s3.y + sp.y, 0.f);
            *reinterpret_cast<float2*>(op) = o;
        }
    }
}

// ---------------------------------------------------------------------------
// Fallback path (ws too small / NUMENT too big): direct vector scatter.
// ---------------------------------------------------------------------------
__global__ void rwb_f32_kernel(const float* __restrict__ rel, const float* __restrict__ W,
                               const float* __restrict__ b, float* __restrict__ rwb, int R) {
    const int k = blockIdx.x;
    const int n = threadIdx.x;
    __shared__ float relk[128];
    relk[n] = rel[(size_t)k * 128 + n];
    __syncthreads();
    const float4* w4 = reinterpret_cast<const float4*>(W + (size_t)n * 128);
    const float4* r4 = reinterpret_cast<const float4*>(relk);
    float acc = 0.f;
#pragma unroll
    for (int i = 0; i < 32; ++i) {
        float4 a = r4[i], w = w4[i];
        acc += a.x * w.x + a.y * w.y + a.z * w.z + a.w * w.w;
    }
    rwb[(size_t)k * 128 + n] = acc + b[n];
}

__global__ void scatter_vec_kernel(const int* __restrict__ heads, const int* __restrict__ tails,
                                   const int* __restrict__ rels, const float* __restrict__ val,
                                   const float* __restrict__ rwb, float* __restrict__ out,
                                   long long nitems) {
    const long long i = (long long)blockIdx.x * blockDim.x + threadIdx.x;
    if (i >= nitems) return;
    const int e = (int)(i >> 5);
    const int c = (int)(i & 31) * 4;
    const float v = val[e];
    float4 rw = *reinterpret_cast<const float4*>(rwb + (size_t)rels[e] * 128 + c);
    float* pt = out + (size_t)tails[e] * 128 + c;
    float* ph = out + (size_t)heads[e] * 128 + c;
    unsafeAtomicAdd(pt + 0, v * rw.x); unsafeAtomicAdd(pt + 1, v * rw.y);
    unsafeAtomicAdd(pt + 2, v * rw.z); unsafeAtomicAdd(pt + 3, v * rw.w);
    unsafeAtomicAdd(ph + 0, v * rw.x); unsafeAtomicAdd(ph + 1, v * rw.y);
    unsafeAtomicAdd(ph + 2, v * rw.z); unsafeAtomicAdd(ph + 3, v * rw.w);
}

__global__ void relu_kernel(float* __restrict__ out, int n4) {
    const int i = blockIdx.x * blockDim.x + threadIdx.x;
    if (i >= n4) return;
    float4* p = reinterpret_cast<float4*>(out) + i;
    float4 v = *p;
    v.x = fmaxf(v.x, 0.f); v.y = fmaxf(v.y, 0.f);
    v.z = fmaxf(v.z, 0.f); v.w = fmaxf(v.w, 0.f);
    *p = v;
}

// ---------------------------------------------------------------------------
extern "C" void kernel_launch(void* const* d_in, const int* in_sizes, int n_in,
                              void* d_out, int out_size, void* d_ws, size_t ws_size,
                              hipStream_t stream) {
    // inputs: 0 local_entity [B*M] (shape only), 1 heads [E], 2 tails [E],
    //         3 rels [E], 4 val [E], 5 rel_features [R*D], 6 W [D*D], 7 b [D]
    const int* heads = (const int*)d_in[1];
    const int* tails = (const int*)d_in[2];
    const int* rels  = (const int*)d_in[3];
    const float* val  = (const float*)d_in[4];
    const float* relf = (const float*)d_in[5];
    const float* W    = (const float*)d_in[6];
    const float* b    = (const float*)d_in[7];
    float* out = (float*)d_out;

    const int NUMENT = in_sizes[0];          // 16000
    const int E      = in_sizes[1];          // 2,000,000
    const int D      = in_sizes[7];          // 128
    const int R      = in_sizes[5] / D;      // 2000

    const int NB = (NUMENT + EPB - 1) / EPB; // 500 buckets
    // expected endpoints/bucket = 2E*EPB/NUMENT (=8000); cap at mean+12.5%+512
    const long long mean = (2LL * E * EPB) / (NUMENT > 0 ? NUMENT : 1);
    int CAPB = (int)(mean + mean / 8 + 512);

    const size_t rwb_bytes = (size_t)R * D * sizeof(_Float16);          // 512 KB
    const size_t off_gcnt  = (rwb_bytes + 255) & ~(size_t)255;
    const size_t gcnt_b    = (size_t)NB * sizeof(int);
    const size_t off_slots = (off_gcnt + gcnt_b + 255) & ~(size_t)255;
    const size_t slots_b   = (size_t)NB * CAPB * sizeof(uint2);         // ~38 MB

    if (NB <= MAXNB && R < (1 << 24) &&
        ws_size >= off_slots + slots_b) {
        _Float16* rwb = (_Float16*)d_ws;
        int* gcnt     = (int*)((char*)d_ws + off_gcnt);
        uint2* slots  = (uint2*)((char*)d_ws + off_slots);

        hipMemsetAsync(gcnt, 0, gcnt_b, stream);
        hipMemsetAsync(out, 0, (size_t)out_size * sizeof(float), stream);
        rwb_row_kernel<<<R, 128, 0, stream>>>(relf, W, b, rwb, R);
        bin_kernel<<<(E + FPB - 1) / FPB, 256, 0, stream>>>(
            heads, tails, rels, val, gcnt, slots, rwb, out, E, NB, CAPB);
        gather_kernel<<<NB, 256, 0, stream>>>(slots, gcnt, rwb, out, NUMENT, CAPB);
    } else {
        // fallback: accumulate directly into out (slow but small-ws safe)
        float* rwb = (float*)d_ws;           // R*D fp32 (~1 MB)
        hipMemsetAsync(out, 0, (size_t)out_size * sizeof(float), stream);
        rwb_f32_kernel<<<R, 128, 0, stream>>>(relf, W, b, rwb, R);
        const long long items = (long long)E * 32;
        scatter_vec_kernel<<<(unsigned)((items + 255) / 256), 256, 0, stream>>>(
            heads, tails, rels, val, rwb, out, items);
        relu_kernel<<<(out_size / 4 + 255) / 256, 256, 0, stream>>>(out, out_size / 4);
    }
}

// Round 4
// 319.488 us; speedup vs baseline: 8.6708x; 1.0854x over previous
//
#include <hip/hip_runtime.h>
#include <hip/hip_bf16.h>
#include <cstdint>

typedef _Float16 half2v __attribute__((ext_vector_type(2)));

#define EPB   32        // entities per bucket
#define MAXNB 1024      // max buckets supported by LDS histogram (NUMENT <= 32768)
#define FPB   4096      // facts per bin-block
#define FPT   16        // facts per thread (256 threads/block)
#define SORTMAX 12288   // max list length sortable in gather LDS (u16 idx, 24 KB)

// ---------------------------------------------------------------------------
// Kernel 1: RWB[r][n] = dot(rel_features[r,:], W[n,:]) + b[n]   (fp16, [R][128])
// Row-major: gather reads row r as 256 contiguous bytes (L2-resident table).
// ---------------------------------------------------------------------------
__global__ void rwb_row_kernel(const float* __restrict__ rel, const float* __restrict__ W,
                               const float* __restrict__ b, _Float16* __restrict__ rwb,
                               int R) {
    const int k = blockIdx.x;        // relation index
    const int n = threadIdx.x;       // output feature (0..127)
    __shared__ float relk[128];
    relk[n] = rel[(size_t)k * 128 + n];
    __syncthreads();
    const float4* w4 = reinterpret_cast<const float4*>(W + (size_t)n * 128);
    const float4* r4 = reinterpret_cast<const float4*>(relk);
    float acc = 0.f;
#pragma unroll
    for (int i = 0; i < 32; ++i) {
        float4 a = r4[i], w = w4[i];
        acc += a.x * w.x + a.y * w.y + a.z * w.z + a.w * w.w;
    }
    rwb[(size_t)k * 128 + n] = (_Float16)(acc + b[n]);
}

// ---------------------------------------------------------------------------
// Spill path for bucket-capacity overflow (statistically unreachable:
// per-bucket endpoints ~Poisson(8000), CAPB gives >10 sigma). Guard only.
// ---------------------------------------------------------------------------
__device__ __noinline__ void spill_add(float* __restrict__ out, const _Float16* __restrict__ rwb,
                                       int v, int r, float val) {
    float* o = out + (size_t)v * 128;
    const _Float16* rw = rwb + (size_t)r * 128;
    for (int n = 0; n < 128; ++n) unsafeAtomicAdd(o + n, val * (float)rw[n]);
}

// ---------------------------------------------------------------------------
// Kernel 2: bin endpoints into per-bucket lists.  (UNCHANGED — ~105us by
// subtraction; this round isolates the gather fix. Next target.)
// payload: x = (local_entity<<24) | rel, y = bits(val)
// ---------------------------------------------------------------------------
__global__ __launch_bounds__(256) void bin_kernel(
    const int* __restrict__ heads, const int* __restrict__ tails,
    const int* __restrict__ rels, const float* __restrict__ val,
    int* __restrict__ gcnt, uint2* __restrict__ slots,
    const _Float16* __restrict__ rwb, float* __restrict__ out,
    int E, int NB, int CAPB) {
    __shared__ int cnt[MAXNB];
    __shared__ int gbase[MAXNB];
    const int t = threadIdx.x;
    for (int k = t; k < NB; k += 256) cnt[k] = 0;
    __syncthreads();

    const int base = blockIdx.x * FPB;
    unsigned keyT[FPT], keyH[FPT], prT[FPT], prH[FPT];
    float fv[FPT];
#pragma unroll
    for (int u = 0; u < FPT; ++u) {
        const int i = base + u * 256 + t;
        prT[u] = 0xFFFFFFFFu;
        prH[u] = 0xFFFFFFFFu;
        if (i < E) {
            const int tl = tails[i], hd = heads[i], r = rels[i];
            fv[u] = val[i];
            const int bt = tl >> 5, bh = hd >> 5;            // EPB = 32
            keyT[u] = ((unsigned)(tl & 31) << 24) | (unsigned)r;
            keyH[u] = ((unsigned)(hd & 31) << 24) | (unsigned)r;
            const int rt = atomicAdd(&cnt[bt], 1);           // LDS int rank (native)
            const int rh = atomicAdd(&cnt[bh], 1);
            prT[u] = ((unsigned)bt << 16) | (unsigned)rt;    // rank < 8192 fits
            prH[u] = ((unsigned)bh << 16) | (unsigned)rh;
        }
    }
    __syncthreads();
    for (int k = t; k < NB; k += 256) {
        const int c = cnt[k];
        gbase[k] = c ? atomicAdd(&gcnt[k], c) : 0;           // 1 atomic / bucket / block
    }
    __syncthreads();
#pragma unroll
    for (int u = 0; u < FPT; ++u) {
        if (prT[u] != 0xFFFFFFFFu) {
            {
                const int b = (int)(prT[u] >> 16);
                const int pos = gbase[b] + (int)(prT[u] & 0xFFFFu);
                uint2 pk; pk.x = keyT[u]; pk.y = __float_as_uint(fv[u]);
                if (pos < CAPB) slots[(size_t)b * CAPB + pos] = pk;
                else spill_add(out, rwb, (b << 5) | (int)(keyT[u] >> 24),
                               (int)(keyT[u] & 0xFFFFFFu), fv[u]);
            }
            {
                const int b = (int)(prH[u] >> 16);
                const int pos = gbase[b] + (int)(prH[u] & 0xFFFFu);
                uint2 pk; pk.x = keyH[u]; pk.y = __float_as_uint(fv[u]);
                if (pos < CAPB) slots[(size_t)b * CAPB + pos] = pk;
                else spill_add(out, rwb, (b << 5) | (int)(keyH[u] >> 24),
                               (int)(keyH[u] & 0xFFFFFFu), fv[u]);
            }
        }
    }
}

// ---------------------------------------------------------------------------
// Kernel 3: one block (512 thr, 8 waves) per bucket.
// Phase A: counting-sort the bucket list BY ENTITY into a u16 index array in
// LDS (24 KB; two passes over the L2-hot list; 32 histogram counters).
// Phase B: each wave owns 4 entities and walks its contiguous sorted run,
// accumulating into 2 VGPRs/lane (lane l = features 2l,2l+1). No LDS writes
// in the hot loop -> no aliasing RMW chain (round-3's 124cyc/entry cost);
// loads are independent, 8 in flight.
// ---------------------------------------------------------------------------
__global__ __launch_bounds__(512) void gather_kernel(
    const uint2* __restrict__ slots, const int* __restrict__ gcnt,
    const _Float16* __restrict__ rwb, float* __restrict__ out,
    int NUMENT, int CAPB) {
    __shared__ unsigned short sidx[SORTMAX];   // 24 KB
    __shared__ int cnt[EPB], basep[EPB], cnt2[EPB];
    const int t = threadIdx.x;
    const int b = blockIdx.x;
    if (t < EPB) { cnt[t] = 0; cnt2[t] = 0; }
    __syncthreads();

    int deg = gcnt[b];
    if (deg > CAPB) deg = CAPB;        // overflow entries were spilled by bin
    if (deg > SORTMAX) deg = SORTMAX;  // host guarantees CAPB <= SORTMAX
    const uint2* sl = slots + (size_t)b * CAPB;

    // Phase A pass 1: per-entity counts
    for (int k = t; k < deg; k += 512)
        atomicAdd(&cnt[(int)(sl[k].x >> 24)], 1);
    __syncthreads();
    if (t == 0) {
        int s = 0;
#pragma unroll
        for (int i = 0; i < EPB; ++i) { basep[i] = s; s += cnt[i]; }
    }
    __syncthreads();
    // Phase A pass 2: rank + place index (list is L2-hot now)
    for (int k = t; k < deg; k += 512) {
        const int le = (int)(sl[k].x >> 24);
        const int r = atomicAdd(&cnt2[le], 1);
        sidx[basep[le] + r] = (unsigned short)k;
    }
    __syncthreads();

    // Phase B: register accumulation over sorted runs
    const int wv = t >> 6, lane = t & 63;
    const unsigned* rwb32 = reinterpret_cast<const unsigned*>(rwb);
#pragma unroll
    for (int ei = 0; ei < 4; ++ei) {
        const int le = wv * 4 + ei;
        const int vent = b * EPB + le;
        const int s0 = basep[le], c = cnt[le];
        float a0 = 0.f, a1 = 0.f;
        int j = 0;
        for (; j + 8 <= c; j += 8) {
            int idx[8];
#pragma unroll
            for (int u = 0; u < 8; ++u) idx[u] = sidx[s0 + j + u];  // ds_read_u16 broadcast
            uint2 e[8];
#pragma unroll
            for (int u = 0; u < 8; ++u) e[u] = sl[idx[u]];          // wave-uniform 8B, L2
            unsigned rw[8];
#pragma unroll
            for (int u = 0; u < 8; ++u)
                rw[u] = rwb32[(size_t)(e[u].x & 0xFFFFFFu) * 64 + lane]; // 256B row, L2
#pragma unroll
            for (int u = 0; u < 8; ++u) {
                const float w = __uint_as_float(e[u].y);
                const half2v h = __builtin_bit_cast(half2v, rw[u]);
                a0 += w * (float)h[0];
                a1 += w * (float)h[1];
            }
        }
        for (; j < c; ++j) {
            const int idx = sidx[s0 + j];
            const uint2 e = sl[idx];
            const float w = __uint_as_float(e.y);
            const unsigned rwv = rwb32[(size_t)(e.x & 0xFFFFFFu) * 64 + lane];
            const half2v h = __builtin_bit_cast(half2v, rwv);
            a0 += w * (float)h[0];
            a1 += w * (float)h[1];
        }
        if (vent < NUMENT) {
            float* op = out + (size_t)vent * 128 + 2 * lane;
            float2 sp = *reinterpret_cast<const float2*>(op);  // spill contrib (normally 0)
            float2 o;
            o.x = fmaxf(a0 + sp.x, 0.f);
            o.y = fmaxf(a1 + sp.y, 0.f);
            *reinterpret_cast<float2*>(op) = o;
        }
    }
}

// ---------------------------------------------------------------------------
// Fallback path (ws too small / NUMENT too big): direct vector scatter.
// ---------------------------------------------------------------------------
__global__ void rwb_f32_kernel(const float* __restrict__ rel, const float* __restrict__ W,
                               const float* __restrict__ b, float* __restrict__ rwb, int R) {
    const int k = blockIdx.x;
    const int n = threadIdx.x;
    __shared__ float relk[128];
    relk[n] = rel[(size_t)k * 128 + n];
    __syncthreads();
    const float4* w4 = reinterpret_cast<const float4*>(W + (size_t)n * 128);
    const float4* r4 = reinterpret_cast<const float4*>(relk);
    float acc = 0.f;
#pragma unroll
    for (int i = 0; i < 32; ++i) {
        float4 a = r4[i], w = w4[i];
        acc += a.x * w.x + a.y * w.y + a.z * w.z + a.w * w.w;
    }
    rwb[(size_t)k * 128 + n] = acc + b[n];
}

__global__ void scatter_vec_kernel(const int* __restrict__ heads, const int* __restrict__ tails,
                                   const int* __restrict__ rels, const float* __restrict__ val,
                                   const float* __restrict__ rwb, float* __restrict__ out,
                                   long long nitems) {
    const long long i = (long long)blockIdx.x * blockDim.x + threadIdx.x;
    if (i >= nitems) return;
    const int e = (int)(i >> 5);
    const int c = (int)(i & 31) * 4;
    const float v = val[e];
    float4 rw = *reinterpret_cast<const float4*>(rwb + (size_t)rels[e] * 128 + c);
    float* pt = out + (size_t)tails[e] * 128 + c;
    float* ph = out + (size_t)heads[e] * 128 + c;
    unsafeAtomicAdd(pt + 0, v * rw.x); unsafeAtomicAdd(pt + 1, v * rw.y);
    unsafeAtomicAdd(pt + 2, v * rw.z); unsafeAtomicAdd(pt + 3, v * rw.w);
    unsafeAtomicAdd(ph + 0, v * rw.x); unsafeAtomicAdd(ph + 1, v * rw.y);
    unsafeAtomicAdd(ph + 2, v * rw.z); unsafeAtomicAdd(ph + 3, v * rw.w);
}

__global__ void relu_kernel(float* __restrict__ out, int n4) {
    const int i = blockIdx.x * blockDim.x + threadIdx.x;
    if (i >= n4) return;
    float4* p = reinterpret_cast<float4*>(out) + i;
    float4 v = *p;
    v.x = fmaxf(v.x, 0.f); v.y = fmaxf(v.y, 0.f);
    v.z = fmaxf(v.z, 0.f); v.w = fmaxf(v.w, 0.f);
    *p = v;
}

// ---------------------------------------------------------------------------
extern "C" void kernel_launch(void* const* d_in, const int* in_sizes, int n_in,
                              void* d_out, int out_size, void* d_ws, size_t ws_size,
                              hipStream_t stream) {
    // inputs: 0 local_entity [B*M] (shape only), 1 heads [E], 2 tails [E],
    //         3 rels [E], 4 val [E], 5 rel_features [R*D], 6 W [D*D], 7 b [D]
    const int* heads = (const int*)d_in[1];
    const int* tails = (const int*)d_in[2];
    const int* rels  = (const int*)d_in[3];
    const float* val  = (const float*)d_in[4];
    const float* relf = (const float*)d_in[5];
    const float* W    = (const float*)d_in[6];
    const float* b    = (const float*)d_in[7];
    float* out = (float*)d_out;

    const int NUMENT = in_sizes[0];          // 16000
    const int E      = in_sizes[1];          // 2,000,000
    const int D      = in_sizes[7];          // 128
    const int R      = in_sizes[5] / D;      // 2000

    const int NB = (NUMENT + EPB - 1) / EPB; // 500 buckets
    // expected endpoints/bucket = 2E*EPB/NUMENT (=8000); cap at mean+12.5%+512
    const long long mean = (2LL * E * EPB) / (NUMENT > 0 ? NUMENT : 1);
    int CAPB = (int)(mean + mean / 8 + 512);

    const size_t rwb_bytes = (size_t)R * D * sizeof(_Float16);          // 512 KB
    const size_t off_gcnt  = (rwb_bytes + 255) & ~(size_t)255;
    const size_t gcnt_b    = (size_t)NB * sizeof(int);
    const size_t off_slots = (off_gcnt + gcnt_b + 255) & ~(size_t)255;
    const size_t slots_b   = (size_t)NB * CAPB * sizeof(uint2);         // ~38 MB

    if (NB <= MAXNB && R < (1 << 24) && CAPB <= SORTMAX &&
        ws_size >= off_slots + slots_b) {
        _Float16* rwb = (_Float16*)d_ws;
        int* gcnt     = (int*)((char*)d_ws + off_gcnt);
        uint2* slots  = (uint2*)((char*)d_ws + off_slots);

        hipMemsetAsync(gcnt, 0, gcnt_b, stream);
        hipMemsetAsync(out, 0, (size_t)out_size * sizeof(float), stream);
        rwb_row_kernel<<<R, 128, 0, stream>>>(relf, W, b, rwb, R);
        bin_kernel<<<(E + FPB - 1) / FPB, 256, 0, stream>>>(
            heads, tails, rels, val, gcnt, slots, rwb, out, E, NB, CAPB);
        gather_kernel<<<NB, 512, 0, stream>>>(slots, gcnt, rwb, out, NUMENT, CAPB);
    } else {
        // fallback: accumulate directly into out (slow but small-ws safe)
        float* rwb = (float*)d_ws;           // R*D fp32 (~1 MB)
        hipMemsetAsync(out, 0, (size_t)out_size * sizeof(float), stream);
        rwb_f32_kernel<<<R, 128, 0, stream>>>(relf, W, b, rwb, R);
        const long long items = (long long)E * 32;
        scatter_vec_kernel<<<(unsigned)((items + 255) / 256), 256, 0, stream>>>(
            heads, tails, rels, val, rwb, out, items);
        relu_kernel<<<(out_size / 4 + 255) / 256, 256, 0, stream>>>(out, out_size / 4);
    }
}

// Round 5
// 210.837 us; speedup vs baseline: 13.1391x; 1.5153x over previous
//
#include <hip/hip_runtime.h>
#include <hip/hip_bf16.h>
#include <cstdint>

typedef _Float16 half2v __attribute__((ext_vector_type(2)));

#define EPB   16        // entities per bucket
#define MAXNB 1024      // max buckets for bin LDS histogram (NUMENT <= 16384)
#define FPB   4096      // facts per bin-block
#define FPT   16        // facts per thread (256 threads/block)
#define SORTCAP 4608    // gather LDS payload capacity (36 KB)
#define CPT   9         // ceil(SORTCAP / 512) register-held entries per thread

// ---------------------------------------------------------------------------
// Kernel 1: RWB[r][n] = dot(rel_features[r,:], W[n,:]) + b[n]   (fp16, [R][128])
// ---------------------------------------------------------------------------
__global__ void rwb_row_kernel(const float* __restrict__ rel, const float* __restrict__ W,
                               const float* __restrict__ b, _Float16* __restrict__ rwb,
                               int R) {
    const int k = blockIdx.x;        // relation index
    const int n = threadIdx.x;       // output feature (0..127)
    __shared__ float relk[128];
    relk[n] = rel[(size_t)k * 128 + n];
    __syncthreads();
    const float4* w4 = reinterpret_cast<const float4*>(W + (size_t)n * 128);
    const float4* r4 = reinterpret_cast<const float4*>(relk);
    float acc = 0.f;
#pragma unroll
    for (int i = 0; i < 32; ++i) {
        float4 a = r4[i], w = w4[i];
        acc += a.x * w.x + a.y * w.y + a.z * w.z + a.w * w.w;
    }
    rwb[(size_t)k * 128 + n] = (_Float16)(acc + b[n]);
}

// ---------------------------------------------------------------------------
// Spill path for bucket-capacity overflow (CAPB ~ mean + >9 sigma; guard only).
// ---------------------------------------------------------------------------
__device__ __noinline__ void spill_add(float* __restrict__ out, const _Float16* __restrict__ rwb,
                                       int v, int r, float val) {
    float* o = out + (size_t)v * 128;
    const _Float16* rw = rwb + (size_t)r * 128;
    for (int n = 0; n < 128; ++n) unsafeAtomicAdd(o + n, val * (float)rw[n]);
}

// ---------------------------------------------------------------------------
// Kernel 2: bin endpoints into per-bucket lists (bucket = entity >> 4).
// payload: x = (local_entity<<24) | rel  (le is 4 bits), y = bits(val)
// ---------------------------------------------------------------------------
__global__ __launch_bounds__(256) void bin_kernel(
    const int* __restrict__ heads, const int* __restrict__ tails,
    const int* __restrict__ rels, const float* __restrict__ val,
    int* __restrict__ gcnt, uint2* __restrict__ slots,
    const _Float16* __restrict__ rwb, float* __restrict__ out,
    int E, int NB, int CAPB) {
    __shared__ int cnt[MAXNB];
    __shared__ int gbase[MAXNB];
    const int t = threadIdx.x;
    for (int k = t; k < NB; k += 256) cnt[k] = 0;
    __syncthreads();

    const int base = blockIdx.x * FPB;
    unsigned keyT[FPT], keyH[FPT], prT[FPT], prH[FPT];
    float fv[FPT];
#pragma unroll
    for (int u = 0; u < FPT; ++u) {
        const int i = base + u * 256 + t;
        prT[u] = 0xFFFFFFFFu;
        prH[u] = 0xFFFFFFFFu;
        if (i < E) {
            const int tl = tails[i], hd = heads[i], r = rels[i];
            fv[u] = val[i];
            const int bt = tl >> 4, bh = hd >> 4;            // EPB = 16
            keyT[u] = ((unsigned)(tl & 15) << 24) | (unsigned)r;
            keyH[u] = ((unsigned)(hd & 15) << 24) | (unsigned)r;
            const int rt = atomicAdd(&cnt[bt], 1);           // LDS int rank (native)
            const int rh = atomicAdd(&cnt[bh], 1);
            prT[u] = ((unsigned)bt << 16) | (unsigned)rt;    // rank < 8192 fits
            prH[u] = ((unsigned)bh << 16) | (unsigned)rh;
        }
    }
    __syncthreads();
    for (int k = t; k < NB; k += 256) {
        const int c = cnt[k];
        gbase[k] = c ? atomicAdd(&gcnt[k], c) : 0;           // 1 atomic / bucket / block
    }
    __syncthreads();
#pragma unroll
    for (int u = 0; u < FPT; ++u) {
        if (prT[u] != 0xFFFFFFFFu) {
            {
                const int b = (int)(prT[u] >> 16);
                const int pos = gbase[b] + (int)(prT[u] & 0xFFFFu);
                uint2 pk; pk.x = keyT[u]; pk.y = __float_as_uint(fv[u]);
                if (pos < CAPB) slots[(size_t)b * CAPB + pos] = pk;
                else spill_add(out, rwb, (b << 4) | (int)(keyT[u] >> 24),
                               (int)(keyT[u] & 0xFFFFFFu), fv[u]);
            }
            {
                const int b = (int)(prH[u] >> 16);
                const int pos = gbase[b] + (int)(prH[u] & 0xFFFFu);
                uint2 pk; pk.x = keyH[u]; pk.y = __float_as_uint(fv[u]);
                if (pos < CAPB) slots[(size_t)b * CAPB + pos] = pk;
                else spill_add(out, rwb, (b << 4) | (int)(keyH[u] >> 24),
                               (int)(keyH[u] & 0xFFFFFFu), fv[u]);
            }
        }
    }
}

// ---------------------------------------------------------------------------
// Kernel 3: one 512-thread block per 16-entity bucket.
// Single global pass: each thread loads <=9 entries (coalesced), ranks them
// via 16 LDS histogram counters, HOLDS them in VGPRs across the prefix
// barrier, then places full payloads into a 36KB sorted LDS array. Phase B
// reads payloads via broadcast ds_read_b64 (no global indirection hop) and
// accumulates in 2 VGPRs/lane. 37KB LDS -> up to 4 blocks/CU; grid NB=1000
// -> ~3.9 blocks/CU (round-4 was grid-capped at 2 blocks/CU, 40% occupancy).
// ---------------------------------------------------------------------------
__global__ __launch_bounds__(512) void gather_kernel(
    const uint2* __restrict__ slots, const int* __restrict__ gcnt,
    const _Float16* __restrict__ rwb, float* __restrict__ out,
    int NUMENT, int CAPB) {
    __shared__ uint2 se[SORTCAP];              // 36 KB sorted payloads
    __shared__ int cnt[EPB], basep[EPB];
    const int t = threadIdx.x;
    const int b = blockIdx.x;
    if (t < EPB) cnt[t] = 0;
    __syncthreads();

    int deg = gcnt[b];
    if (deg > CAPB) deg = CAPB;        // overflow entries were spilled by bin
    const uint2* sl = slots + (size_t)b * CAPB;

    // pass 1: coalesced load, LDS rank, hold in registers
    uint2 e[CPT];
    int rk[CPT];
#pragma unroll
    for (int u = 0; u < CPT; ++u) {
        const int k = t + u * 512;
        rk[u] = -1;
        if (k < deg) {
            e[u] = sl[k];
            rk[u] = atomicAdd(&cnt[(int)(e[u].x >> 24)], 1);
        }
    }
    __syncthreads();
    if (t == 0) {
        int s = 0;
#pragma unroll
        for (int i = 0; i < EPB; ++i) { basep[i] = s; s += cnt[i]; }
    }
    __syncthreads();
#pragma unroll
    for (int u = 0; u < CPT; ++u)
        if (rk[u] >= 0) se[basep[(int)(e[u].x >> 24)] + rk[u]] = e[u];
    __syncthreads();

    // Phase B: 8 waves x 2 entities; register accumulation over sorted runs
    const int wv = t >> 6, lane = t & 63;
    const unsigned* rwb32 = reinterpret_cast<const unsigned*>(rwb);
#pragma unroll
    for (int ei = 0; ei < 2; ++ei) {
        const int le = wv * 2 + ei;
        const int vent = b * EPB + le;
        const int s0 = basep[le], c = cnt[le];
        float a0 = 0.f, a1 = 0.f;
        int j = 0;
        for (; j + 8 <= c; j += 8) {
            uint2 q[8];
#pragma unroll
            for (int u = 0; u < 8; ++u) q[u] = se[s0 + j + u];   // ds_read_b64 broadcast
            unsigned rw[8];
#pragma unroll
            for (int u = 0; u < 8; ++u)
                rw[u] = rwb32[(size_t)(q[u].x & 0xFFFFFFu) * 64 + lane]; // 256B row, L2
#pragma unroll
            for (int u = 0; u < 8; ++u) {
                const float w = __uint_as_float(q[u].y);
                const half2v h = __builtin_bit_cast(half2v, rw[u]);
                a0 += w * (float)h[0];
                a1 += w * (float)h[1];
            }
        }
        for (; j < c; ++j) {
            const uint2 q = se[s0 + j];
            const float w = __uint_as_float(q.y);
            const unsigned rwv = rwb32[(size_t)(q.x & 0xFFFFFFu) * 64 + lane];
            const half2v h = __builtin_bit_cast(half2v, rwv);
            a0 += w * (float)h[0];
            a1 += w * (float)h[1];
        }
        if (vent < NUMENT) {
            float* op = out + (size_t)vent * 128 + 2 * lane;
            float2 sp = *reinterpret_cast<const float2*>(op);  // spill contrib (normally 0)
            float2 o;
            o.x = fmaxf(a0 + sp.x, 0.f);
            o.y = fmaxf(a1 + sp.y, 0.f);
            *reinterpret_cast<float2*>(op) = o;
        }
    }
}

// ---------------------------------------------------------------------------
// Fallback path (ws too small / shape out of range): direct vector scatter.
// ---------------------------------------------------------------------------
__global__ void rwb_f32_kernel(const float* __restrict__ rel, const float* __restrict__ W,
                               const float* __restrict__ b, float* __restrict__ rwb, int R) {
    const int k = blockIdx.x;
    const int n = threadIdx.x;
    __shared__ float relk[128];
    relk[n] = rel[(size_t)k * 128 + n];
    __syncthreads();
    const float4* w4 = reinterpret_cast<const float4*>(W + (size_t)n * 128);
    const float4* r4 = reinterpret_cast<const float4*>(relk);
    float acc = 0.f;
#pragma unroll
    for (int i = 0; i < 32; ++i) {
        float4 a = r4[i], w = w4[i];
        acc += a.x * w.x + a.y * w.y + a.z * w.z + a.w * w.w;
    }
    rwb[(size_t)k * 128 + n] = acc + b[n];
}

__global__ void scatter_vec_kernel(const int* __restrict__ heads, const int* __restrict__ tails,
                                   const int* __restrict__ rels, const float* __restrict__ val,
                                   const float* __restrict__ rwb, float* __restrict__ out,
                                   long long nitems) {
    const long long i = (long long)blockIdx.x * blockDim.x + threadIdx.x;
    if (i >= nitems) return;
    const int e = (int)(i >> 5);
    const int c = (int)(i & 31) * 4;
    const float v = val[e];
    float4 rw = *reinterpret_cast<const float4*>(rwb + (size_t)rels[e] * 128 + c);
    float* pt = out + (size_t)tails[e] * 128 + c;
    float* ph = out + (size_t)heads[e] * 128 + c;
    unsafeAtomicAdd(pt + 0, v * rw.x); unsafeAtomicAdd(pt + 1, v * rw.y);
    unsafeAtomicAdd(pt + 2, v * rw.z); unsafeAtomicAdd(pt + 3, v * rw.w);
    unsafeAtomicAdd(ph + 0, v * rw.x); unsafeAtomicAdd(ph + 1, v * rw.y);
    unsafeAtomicAdd(ph + 2, v * rw.z); unsafeAtomicAdd(ph + 3, v * rw.w);
}

__global__ void relu_kernel(float* __restrict__ out, int n4) {
    const int i = blockIdx.x * blockDim.x + threadIdx.x;
    if (i >= n4) return;
    float4* p = reinterpret_cast<float4*>(out) + i;
    float4 v = *p;
    v.x = fmaxf(v.x, 0.f); v.y = fmaxf(v.y, 0.f);
    v.z = fmaxf(v.z, 0.f); v.w = fmaxf(v.w, 0.f);
    *p = v;
}

// ---------------------------------------------------------------------------
extern "C" void kernel_launch(void* const* d_in, const int* in_sizes, int n_in,
                              void* d_out, int out_size, void* d_ws, size_t ws_size,
                              hipStream_t stream) {
    // inputs: 0 local_entity [B*M] (shape only), 1 heads [E], 2 tails [E],
    //         3 rels [E], 4 val [E], 5 rel_features [R*D], 6 W [D*D], 7 b [D]
    const int* heads = (const int*)d_in[1];
    const int* tails = (const int*)d_in[2];
    const int* rels  = (const int*)d_in[3];
    const float* val  = (const float*)d_in[4];
    const float* relf = (const float*)d_in[5];
    const float* W    = (const float*)d_in[6];
    const float* b    = (const float*)d_in[7];
    float* out = (float*)d_out;

    const int NUMENT = in_sizes[0];          // 16000
    const int E      = in_sizes[1];          // 2,000,000
    const int D      = in_sizes[7];          // 128
    const int R      = in_sizes[5] / D;      // 2000

    const int NB = (NUMENT + EPB - 1) / EPB; // 1000 buckets
    // expected endpoints/bucket = 2E*EPB/NUMENT (=4000, sigma~63);
    // slack mean/16+256 ~ +9.6 sigma at default shape
    const long long mean = (2LL * E * EPB) / (NUMENT > 0 ? NUMENT : 1);
    int CAPB = (int)(mean + mean / 16 + 256);

    const size_t rwb_bytes = (size_t)R * D * sizeof(_Float16);          // 512 KB
    const size_t off_gcnt  = (rwb_bytes + 255) & ~(size_t)255;
    const size_t gcnt_b    = (size_t)NB * sizeof(int);
    const size_t off_slots = (off_gcnt + gcnt_b + 255) & ~(size_t)255;
    const size_t slots_b   = (size_t)NB * CAPB * sizeof(uint2);         // ~36 MB

    if (NB <= MAXNB && R < (1 << 24) && CAPB <= SORTCAP &&
        ws_size >= off_slots + slots_b) {
        _Float16* rwb = (_Float16*)d_ws;
        int* gcnt     = (int*)((char*)d_ws + off_gcnt);
        uint2* slots  = (uint2*)((char*)d_ws + off_slots);

        hipMemsetAsync(gcnt, 0, gcnt_b, stream);
        hipMemsetAsync(out, 0, (size_t)out_size * sizeof(float), stream);
        rwb_row_kernel<<<R, 128, 0, stream>>>(relf, W, b, rwb, R);
        bin_kernel<<<(E + FPB - 1) / FPB, 256, 0, stream>>>(
            heads, tails, rels, val, gcnt, slots, rwb, out, E, NB, CAPB);
        gather_kernel<<<NB, 512, 0, stream>>>(slots, gcnt, rwb, out, NUMENT, CAPB);
    } else {
        // fallback: accumulate directly into out (slow but small-ws safe)
        float* rwb = (float*)d_ws;           // R*D fp32 (~1 MB)
        hipMemsetAsync(out, 0, (size_t)out_size * sizeof(float), stream);
        rwb_f32_kernel<<<R, 128, 0, stream>>>(relf, W, b, rwb, R);
        const long long items = (long long)E * 32;
        scatter_vec_kernel<<<(unsigned)((items + 255) / 256), 256, 0, stream>>>(
            heads, tails, rels, val, rwb, out, items);
        relu_kernel<<<(out_size / 4 + 255) / 256, 256, 0, stream>>>(out, out_size / 4);
    }
}

// Round 6
// 208.669 us; speedup vs baseline: 13.2756x; 1.0104x over previous
//
#include <hip/hip_runtime.h>
#include <hip/hip_bf16.h>
#include <cstdint>

typedef _Float16 half2v __attribute__((ext_vector_type(2)));

#define EPB   16        // entities per bucket
#define MAXNB 1024      // max buckets for bin LDS histogram (NUMENT <= 16384)
#define FPB   8192      // facts per bin-block (512 thr x FPT 16)
#define FPT   16        // facts per thread
#define SORTCAP 4608    // gather LDS payload capacity (u32 -> 18 KB)
#define CPT   9         // ceil(SORTCAP / 512) register-held entries per thread

// payload u32: [31:28]=local entity (4b) | [27:16]=rel (12b, R<4096) | [15:0]=fp16(val)

__device__ __forceinline__ float pay_val(unsigned p) {
    return (float)__builtin_bit_cast(_Float16, (unsigned short)(p & 0xFFFFu));
}

// ---------------------------------------------------------------------------
// Kernel 1: RWB[r][n] = dot(rel_features[r,:], W[n,:]) + b[n]   (fp16, [R][128])
// ---------------------------------------------------------------------------
__global__ void rwb_row_kernel(const float* __restrict__ rel, const float* __restrict__ W,
                               const float* __restrict__ b, _Float16* __restrict__ rwb,
                               int R) {
    const int k = blockIdx.x;        // relation index
    const int n = threadIdx.x;       // output feature (0..127)
    __shared__ float relk[128];
    relk[n] = rel[(size_t)k * 128 + n];
    __syncthreads();
    const float4* w4 = reinterpret_cast<const float4*>(W + (size_t)n * 128);
    const float4* r4 = reinterpret_cast<const float4*>(relk);
    float acc = 0.f;
#pragma unroll
    for (int i = 0; i < 32; ++i) {
        float4 a = r4[i], w = w4[i];
        acc += a.x * w.x + a.y * w.y + a.z * w.z + a.w * w.w;
    }
    rwb[(size_t)k * 128 + n] = (_Float16)(acc + b[n]);
}

// ---------------------------------------------------------------------------
// Spill path for bucket-capacity overflow (CAPB ~ mean + >9 sigma; guard only).
// ---------------------------------------------------------------------------
__device__ __noinline__ void spill_add(float* __restrict__ out, const _Float16* __restrict__ rwb,
                                       int v, unsigned pay) {
    const int r = (int)((pay >> 16) & 0xFFFu);
    const float val = pay_val(pay);
    float* o = out + (size_t)v * 128;
    const _Float16* rw = rwb + (size_t)r * 128;
    for (int n = 0; n < 128; ++n) unsafeAtomicAdd(o + n, val * (float)rw[n]);
}

// ---------------------------------------------------------------------------
// Kernel 2: bin endpoints into per-bucket lists (bucket = entity >> 4).
// 512 thr x FPT16 = 8192 facts/block: runs per (block,bucket) ~16 entries;
// u32 payload halves slot bytes. Round-5 PMC: WRITE_SIZE 117MB for a 36MB
// array (3.3x partial-line amplification) was bin's cost — this attacks both
// factors (payload size, run length).
// ---------------------------------------------------------------------------
__global__ __launch_bounds__(512) void bin_kernel(
    const int* __restrict__ heads, const int* __restrict__ tails,
    const int* __restrict__ rels, const float* __restrict__ val,
    int* __restrict__ gcnt, unsigned* __restrict__ slots,
    const _Float16* __restrict__ rwb, float* __restrict__ out,
    int E, int NB, int CAPB) {
    __shared__ int cnt[MAXNB];
    __shared__ int gbase[MAXNB];
    const int t = threadIdx.x;
    for (int k = t; k < NB; k += 512) cnt[k] = 0;
    __syncthreads();

    const int base = blockIdx.x * FPB;
    unsigned payT[FPT], payH[FPT], prT[FPT], prH[FPT];
#pragma unroll
    for (int u = 0; u < FPT; ++u) {
        const int i = base + u * 512 + t;
        prT[u] = 0xFFFFFFFFu;
        prH[u] = 0xFFFFFFFFu;
        if (i < E) {
            const int tl = tails[i], hd = heads[i], r = rels[i];
            const unsigned hv =
                (unsigned)__builtin_bit_cast(unsigned short, (_Float16)val[i]);
            const int bt = tl >> 4, bh = hd >> 4;            // EPB = 16
            payT[u] = ((unsigned)(tl & 15) << 28) | ((unsigned)r << 16) | hv;
            payH[u] = ((unsigned)(hd & 15) << 28) | ((unsigned)r << 16) | hv;
            const int rt = atomicAdd(&cnt[bt], 1);           // LDS int rank (native)
            const int rh = atomicAdd(&cnt[bh], 1);
            prT[u] = ((unsigned)bt << 16) | (unsigned)rt;    // rank < 16384 fits
            prH[u] = ((unsigned)bh << 16) | (unsigned)rh;
        }
    }
    __syncthreads();
    for (int k = t; k < NB; k += 512) {
        const int c = cnt[k];
        gbase[k] = c ? atomicAdd(&gcnt[k], c) : 0;           // 1 atomic / bucket / block
    }
    __syncthreads();
#pragma unroll
    for (int u = 0; u < FPT; ++u) {
        if (prT[u] != 0xFFFFFFFFu) {
            {
                const int b1 = (int)(prT[u] >> 16);
                const int pos = gbase[b1] + (int)(prT[u] & 0xFFFFu);
                if (pos < CAPB) slots[(size_t)b1 * CAPB + pos] = payT[u];
                else spill_add(out, rwb, (b1 << 4) | (int)(payT[u] >> 28), payT[u]);
            }
            {
                const int b1 = (int)(prH[u] >> 16);
                const int pos = gbase[b1] + (int)(prH[u] & 0xFFFFu);
                if (pos < CAPB) slots[(size_t)b1 * CAPB + pos] = payH[u];
                else spill_add(out, rwb, (b1 << 4) | (int)(payH[u] >> 28), payH[u]);
            }
        }
    }
}

// ---------------------------------------------------------------------------
// Kernel 3: one 512-thread block per 16-entity bucket.
// Single global pass: each thread loads <=9 u32 payloads (coalesced), ranks
// them via 16 LDS counters, holds them in VGPRs across the prefix barrier,
// places them sorted into 18KB LDS. Phase B: 8 waves x 2 entities, broadcast
// ds_read_b32 + L2 rwb row load, 2 fp32 acc VGPRs/lane.
// ---------------------------------------------------------------------------
__global__ __launch_bounds__(512) void gather_kernel(
    const unsigned* __restrict__ slots, const int* __restrict__ gcnt,
    const _Float16* __restrict__ rwb, float* __restrict__ out,
    int NUMENT, int CAPB) {
    __shared__ unsigned se[SORTCAP];           // 18 KB sorted payloads
    __shared__ int cnt[EPB], basep[EPB];
    const int t = threadIdx.x;
    const int b = blockIdx.x;
    if (t < EPB) cnt[t] = 0;
    __syncthreads();

    int deg = gcnt[b];
    if (deg > CAPB) deg = CAPB;        // overflow entries were spilled by bin
    const unsigned* sl = slots + (size_t)b * CAPB;

    // pass 1: coalesced load, LDS rank, hold in registers
    unsigned e[CPT];
    int rk[CPT];
#pragma unroll
    for (int u = 0; u < CPT; ++u) {
        const int k = t + u * 512;
        rk[u] = -1;
        if (k < deg) {
            e[u] = sl[k];
            rk[u] = atomicAdd(&cnt[(int)(e[u] >> 28)], 1);
        }
    }
    __syncthreads();
    if (t == 0) {
        int s = 0;
#pragma unroll
        for (int i = 0; i < EPB; ++i) { basep[i] = s; s += cnt[i]; }
    }
    __syncthreads();
#pragma unroll
    for (int u = 0; u < CPT; ++u)
        if (rk[u] >= 0) se[basep[(int)(e[u] >> 28)] + rk[u]] = e[u];
    __syncthreads();

    // Phase B: 8 waves x 2 entities; register accumulation over sorted runs
    const int wv = t >> 6, lane = t & 63;
    const unsigned* rwb32 = reinterpret_cast<const unsigned*>(rwb);
#pragma unroll
    for (int ei = 0; ei < 2; ++ei) {
        const int le = wv * 2 + ei;
        const int vent = b * EPB + le;
        const int s0 = basep[le], c = cnt[le];
        float a0 = 0.f, a1 = 0.f;
        int j = 0;
        for (; j + 8 <= c; j += 8) {
            unsigned q[8];
#pragma unroll
            for (int u = 0; u < 8; ++u) q[u] = se[s0 + j + u];   // ds_read_b32 broadcast
            unsigned rw[8];
#pragma unroll
            for (int u = 0; u < 8; ++u)
                rw[u] = rwb32[(size_t)((q[u] >> 16) & 0xFFFu) * 64 + lane]; // 256B row, L2
#pragma unroll
            for (int u = 0; u < 8; ++u) {
                const float w = pay_val(q[u]);
                const half2v h = __builtin_bit_cast(half2v, rw[u]);
                a0 += w * (float)h[0];
                a1 += w * (float)h[1];
            }
        }
        for (; j < c; ++j) {
            const unsigned q = se[s0 + j];
            const float w = pay_val(q);
            const unsigned rwv = rwb32[(size_t)((q >> 16) & 0xFFFu) * 64 + lane];
            const half2v h = __builtin_bit_cast(half2v, rwv);
            a0 += w * (float)h[0];
            a1 += w * (float)h[1];
        }
        if (vent < NUMENT) {
            float* op = out + (size_t)vent * 128 + 2 * lane;
            float2 sp = *reinterpret_cast<const float2*>(op);  // spill contrib (normally 0)
            float2 o;
            o.x = fmaxf(a0 + sp.x, 0.f);
            o.y = fmaxf(a1 + sp.y, 0.f);
            *reinterpret_cast<float2*>(op) = o;
        }
    }
}

// ---------------------------------------------------------------------------
// Fallback path (ws too small / shape out of range): direct vector scatter.
// ---------------------------------------------------------------------------
__global__ void rwb_f32_kernel(const float* __restrict__ rel, const float* __restrict__ W,
                               const float* __restrict__ b, float* __restrict__ rwb, int R) {
    const int k = blockIdx.x;
    const int n = threadIdx.x;
    __shared__ float relk[128];
    relk[n] = rel[(size_t)k * 128 + n];
    __syncthreads();
    const float4* w4 = reinterpret_cast<const float4*>(W + (size_t)n * 128);
    const float4* r4 = reinterpret_cast<const float4*>(relk);
    float acc = 0.f;
#pragma unroll
    for (int i = 0; i < 32; ++i) {
        float4 a = r4[i], w = w4[i];
        acc += a.x * w.x + a.y * w.y + a.z * w.z + a.w * w.w;
    }
    rwb[(size_t)k * 128 + n] = acc + b[n];
}

__global__ void scatter_vec_kernel(const int* __restrict__ heads, const int* __restrict__ tails,
                                   const int* __restrict__ rels, const float* __restrict__ val,
                                   const float* __restrict__ rwb, float* __restrict__ out,
                                   long long nitems) {
    const long long i = (long long)blockIdx.x * blockDim.x + threadIdx.x;
    if (i >= nitems) return;
    const int e = (int)(i >> 5);
    const int c = (int)(i & 31) * 4;
    const float v = val[e];
    float4 rw = *reinterpret_cast<const float4*>(rwb + (size_t)rels[e] * 128 + c);
    float* pt = out + (size_t)tails[e] * 128 + c;
    float* ph = out + (size_t)heads[e] * 128 + c;
    unsafeAtomicAdd(pt + 0, v * rw.x); unsafeAtomicAdd(pt + 1, v * rw.y);
    unsafeAtomicAdd(pt + 2, v * rw.z); unsafeAtomicAdd(pt + 3, v * rw.w);
    unsafeAtomicAdd(ph + 0, v * rw.x); unsafeAtomicAdd(ph + 1, v * rw.y);
    unsafeAtomicAdd(ph + 2, v * rw.z); unsafeAtomicAdd(ph + 3, v * rw.w);
}

__global__ void relu_kernel(float* __restrict__ out, int n4) {
    const int i = blockIdx.x * blockDim.x + threadIdx.x;
    if (i >= n4) return;
    float4* p = reinterpret_cast<float4*>(out) + i;
    float4 v = *p;
    v.x = fmaxf(v.x, 0.f); v.y = fmaxf(v.y, 0.f);
    v.z = fmaxf(v.z, 0.f); v.w = fmaxf(v.w, 0.f);
    *p = v;
}

// ---------------------------------------------------------------------------
extern "C" void kernel_launch(void* const* d_in, const int* in_sizes, int n_in,
                              void* d_out, int out_size, void* d_ws, size_t ws_size,
                              hipStream_t stream) {
    // inputs: 0 local_entity [B*M] (shape only), 1 heads [E], 2 tails [E],
    //         3 rels [E], 4 val [E], 5 rel_features [R*D], 6 W [D*D], 7 b [D]
    const int* heads = (const int*)d_in[1];
    const int* tails = (const int*)d_in[2];
    const int* rels  = (const int*)d_in[3];
    const float* val  = (const float*)d_in[4];
    const float* relf = (const float*)d_in[5];
    const float* W    = (const float*)d_in[6];
    const float* b    = (const float*)d_in[7];
    float* out = (float*)d_out;

    const int NUMENT = in_sizes[0];          // 16000
    const int E      = in_sizes[1];          // 2,000,000
    const int D      = in_sizes[7];          // 128
    const int R      = in_sizes[5] / D;      // 2000

    const int NB = (NUMENT + EPB - 1) / EPB; // 1000 buckets
    // expected endpoints/bucket = 2E*EPB/NUMENT (=4000, sigma~63);
    // slack mean/16+256 ~ +9.6 sigma at default shape
    const long long mean = (2LL * E * EPB) / (NUMENT > 0 ? NUMENT : 1);
    int CAPB = (int)(mean + mean / 16 + 256);

    const size_t rwb_bytes = (size_t)R * D * sizeof(_Float16);          // 512 KB
    const size_t off_gcnt  = (rwb_bytes + 255) & ~(size_t)255;
    const size_t gcnt_b    = (size_t)NB * sizeof(int);
    const size_t off_slots = (off_gcnt + gcnt_b + 255) & ~(size_t)255;
    const size_t slots_b   = (size_t)NB * CAPB * sizeof(unsigned);      // ~18 MB

    if (NB <= MAXNB && R < 4096 && CAPB <= SORTCAP &&
        ws_size >= off_slots + slots_b) {
        _Float16* rwb   = (_Float16*)d_ws;
        int* gcnt       = (int*)((char*)d_ws + off_gcnt);
        unsigned* slots = (unsigned*)((char*)d_ws + off_slots);

        hipMemsetAsync(gcnt, 0, gcnt_b, stream);
        hipMemsetAsync(out, 0, (size_t)out_size * sizeof(float), stream);
        rwb_row_kernel<<<R, 128, 0, stream>>>(relf, W, b, rwb, R);
        bin_kernel<<<(E + FPB - 1) / FPB, 512, 0, stream>>>(
            heads, tails, rels, val, gcnt, slots, rwb, out, E, NB, CAPB);
        gather_kernel<<<NB, 512, 0, stream>>>(slots, gcnt, rwb, out, NUMENT, CAPB);
    } else {
        // fallback: accumulate directly into out (slow but small-ws safe)
        float* rwb = (float*)d_ws;           // R*D fp32 (~1 MB)
        hipMemsetAsync(out, 0, (size_t)out_size * sizeof(float), stream);
        rwb_f32_kernel<<<R, 128, 0, stream>>>(relf, W, b, rwb, R);
        const long long items = (long long)E * 32;
        scatter_vec_kernel<<<(unsigned)((items + 255) / 256), 256, 0, stream>>>(
            heads, tails, rels, val, rwb, out, items);
        relu_kernel<<<(out_size / 4 + 255) / 256, 256, 0, stream>>>(out, out_size / 4);
    }
}

// Round 7
// 205.530 us; speedup vs baseline: 13.4784x; 1.0153x over previous
//
#include <hip/hip_runtime.h>
#include <hip/hip_bf16.h>
#include <cstdint>

typedef _Float16 half2v __attribute__((ext_vector_type(2)));

#define EPB   16        // entities per bucket
#define MAXNB 1024      // max buckets for bin LDS histogram (NUMENT <= 16384)
#define FPB   8192      // facts per bin-block (512 thr x FPT 16)
#define FPT   16        // facts per thread
#define SORTCAP 4608    // gather LDS payload capacity (u32 -> 18 KB)
#define CPT   9         // ceil(SORTCAP / 512) register-held entries per thread

// payload u32: [31:28]=local entity (4b) | [27:16]=rel (12b, R<4096) | [15:0]=fp16(val)

__device__ __forceinline__ float pay_val(unsigned p) {
    return (float)__builtin_bit_cast(_Float16, (unsigned short)(p & 0xFFFFu));
}

// ---------------------------------------------------------------------------
// Kernel 1: RWB[r][n] = dot(rel_features[r,:], W[n,:]) + b[n]   (fp16, [R][128])
// ---------------------------------------------------------------------------
__global__ void rwb_row_kernel(const float* __restrict__ rel, const float* __restrict__ W,
                               const float* __restrict__ b, _Float16* __restrict__ rwb,
                               int R) {
    const int k = blockIdx.x;        // relation index
    const int n = threadIdx.x;       // output feature (0..127)
    __shared__ float relk[128];
    relk[n] = rel[(size_t)k * 128 + n];
    __syncthreads();
    const float4* w4 = reinterpret_cast<const float4*>(W + (size_t)n * 128);
    const float4* r4 = reinterpret_cast<const float4*>(relk);
    float acc = 0.f;
#pragma unroll
    for (int i = 0; i < 32; ++i) {
        float4 a = r4[i], w = w4[i];
        acc += a.x * w.x + a.y * w.y + a.z * w.z + a.w * w.w;
    }
    rwb[(size_t)k * 128 + n] = (_Float16)(acc + b[n]);
}

// ---------------------------------------------------------------------------
// Spill path for bucket-capacity overflow (CAPB ~ mean + >9 sigma; guard only).
// ---------------------------------------------------------------------------
__device__ __noinline__ void spill_add(float* __restrict__ out, const _Float16* __restrict__ rwb,
                                       int v, unsigned pay) {
    const int r = (int)((pay >> 16) & 0xFFFu);
    const float val = pay_val(pay);
    float* o = out + (size_t)v * 128;
    const _Float16* rw = rwb + (size_t)r * 128;
    for (int n = 0; n < 128; ++n) unsafeAtomicAdd(o + n, val * (float)rw[n]);
}

// ---------------------------------------------------------------------------
// Kernel 2: bin endpoints into per-bucket lists (bucket = entity >> 4).
// UNCHANGED from round 6 (this round isolates the gather VALU fix).
// ---------------------------------------------------------------------------
__global__ __launch_bounds__(512) void bin_kernel(
    const int* __restrict__ heads, const int* __restrict__ tails,
    const int* __restrict__ rels, const float* __restrict__ val,
    int* __restrict__ gcnt, unsigned* __restrict__ slots,
    const _Float16* __restrict__ rwb, float* __restrict__ out,
    int E, int NB, int CAPB) {
    __shared__ int cnt[MAXNB];
    __shared__ int gbase[MAXNB];
    const int t = threadIdx.x;
    for (int k = t; k < NB; k += 512) cnt[k] = 0;
    __syncthreads();

    const int base = blockIdx.x * FPB;
    unsigned payT[FPT], payH[FPT], prT[FPT], prH[FPT];
#pragma unroll
    for (int u = 0; u < FPT; ++u) {
        const int i = base + u * 512 + t;
        prT[u] = 0xFFFFFFFFu;
        prH[u] = 0xFFFFFFFFu;
        if (i < E) {
            const int tl = tails[i], hd = heads[i], r = rels[i];
            const unsigned hv =
                (unsigned)__builtin_bit_cast(unsigned short, (_Float16)val[i]);
            const int bt = tl >> 4, bh = hd >> 4;            // EPB = 16
            payT[u] = ((unsigned)(tl & 15) << 28) | ((unsigned)r << 16) | hv;
            payH[u] = ((unsigned)(hd & 15) << 28) | ((unsigned)r << 16) | hv;
            const int rt = atomicAdd(&cnt[bt], 1);           // LDS int rank (native)
            const int rh = atomicAdd(&cnt[bh], 1);
            prT[u] = ((unsigned)bt << 16) | (unsigned)rt;    // rank < 16384 fits
            prH[u] = ((unsigned)bh << 16) | (unsigned)rh;
        }
    }
    __syncthreads();
    for (int k = t; k < NB; k += 512) {
        const int c = cnt[k];
        gbase[k] = c ? atomicAdd(&gcnt[k], c) : 0;           // 1 atomic / bucket / block
    }
    __syncthreads();
#pragma unroll
    for (int u = 0; u < FPT; ++u) {
        if (prT[u] != 0xFFFFFFFFu) {
            {
                const int b1 = (int)(prT[u] >> 16);
                const int pos = gbase[b1] + (int)(prT[u] & 0xFFFFu);
                if (pos < CAPB) slots[(size_t)b1 * CAPB + pos] = payT[u];
                else spill_add(out, rwb, (b1 << 4) | (int)(payT[u] >> 28), payT[u]);
            }
            {
                const int b1 = (int)(prH[u] >> 16);
                const int pos = gbase[b1] + (int)(prH[u] & 0xFFFFu);
                if (pos < CAPB) slots[(size_t)b1 * CAPB + pos] = payH[u];
                else spill_add(out, rwb, (b1 << 4) | (int)(payH[u] >> 28), payH[u]);
            }
        }
    }
}

// ---------------------------------------------------------------------------
// Kernel 3: one 512-thread block per 16-entity bucket.
// Phase A unchanged. Phase B: every per-entry quantity except the 2 FMAs is
// WAVE-UNIFORM (payload comes from a broadcast ds_read). readfirstlane moves
// rel-extract / row-base / w-unpack to the SALU pipe (round-6 PMC: VALUBusy
// 72% at 3.6% HBM = per-lane VALU burning uniform work). The row load becomes
// saddr-form global_load_dword (scalar base + lane offset); the two f16->f32
// FMAs should contract to v_fma_mix_f32.
// ---------------------------------------------------------------------------
__global__ __launch_bounds__(512) void gather_kernel(
    const unsigned* __restrict__ slots, const int* __restrict__ gcnt,
    const _Float16* __restrict__ rwb, float* __restrict__ out,
    int NUMENT, int CAPB) {
    __shared__ unsigned se[SORTCAP];           // 18 KB sorted payloads
    __shared__ int cnt[EPB], basep[EPB];
    const int t = threadIdx.x;
    const int b = blockIdx.x;
    if (t < EPB) cnt[t] = 0;
    __syncthreads();

    int deg = gcnt[b];
    if (deg > CAPB) deg = CAPB;        // overflow entries were spilled by bin
    const unsigned* sl = slots + (size_t)b * CAPB;

    // Phase A: coalesced load, LDS rank, hold in registers, sorted placement
    unsigned e[CPT];
    int rk[CPT];
#pragma unroll
    for (int u = 0; u < CPT; ++u) {
        const int k = t + u * 512;
        rk[u] = -1;
        if (k < deg) {
            e[u] = sl[k];
            rk[u] = atomicAdd(&cnt[(int)(e[u] >> 28)], 1);
        }
    }
    __syncthreads();
    if (t == 0) {
        int s = 0;
#pragma unroll
        for (int i = 0; i < EPB; ++i) { basep[i] = s; s += cnt[i]; }
    }
    __syncthreads();
#pragma unroll
    for (int u = 0; u < CPT; ++u)
        if (rk[u] >= 0) se[basep[(int)(e[u] >> 28)] + rk[u]] = e[u];
    __syncthreads();

    // Phase B: 8 waves x 2 entities; scalarized uniform work + 2 FMA/lane/entry
    const int wv = t >> 6, lane = t & 63;
    const int loff = lane * 2;                 // _Float16 element offset in row
#pragma unroll
    for (int ei = 0; ei < 2; ++ei) {
        const int le = wv * 2 + ei;
        const int vent = b * EPB + le;
        const int s0 = basep[le], c = cnt[le];
        float a0 = 0.f, a1 = 0.f;
        int j = 0;
        for (; j + 8 <= c; j += 8) {
            unsigned q[8];
#pragma unroll
            for (int u = 0; u < 8; ++u) q[u] = se[s0 + j + u];   // ds_read_b32 broadcast
            unsigned qs[8];
#pragma unroll
            for (int u = 0; u < 8; ++u) qs[u] = __builtin_amdgcn_readfirstlane(q[u]);
            unsigned rw[8];
#pragma unroll
            for (int u = 0; u < 8; ++u) {
                const _Float16* rowp = rwb + (size_t)((qs[u] >> 16) & 0xFFFu) * 128;
                rw[u] = *reinterpret_cast<const unsigned*>(rowp + loff);  // saddr + v_lane
            }
#pragma unroll
            for (int u = 0; u < 8; ++u) {
                const float w = (float)__builtin_bit_cast(
                    _Float16, (unsigned short)(qs[u] & 0xFFFFu));   // cvt, SGPR src
                const half2v h = __builtin_bit_cast(half2v, rw[u]);
                a0 = fmaf(w, (float)h[0], a0);   // -> v_fma_mix_f32
                a1 = fmaf(w, (float)h[1], a1);
            }
        }
        for (; j < c; ++j) {
            const unsigned q = se[s0 + j];
            const unsigned qs = __builtin_amdgcn_readfirstlane(q);
            const _Float16* rowp = rwb + (size_t)((qs >> 16) & 0xFFFu) * 128;
            const unsigned rwv = *reinterpret_cast<const unsigned*>(rowp + loff);
            const float w = (float)__builtin_bit_cast(
                _Float16, (unsigned short)(qs & 0xFFFFu));
            const half2v h = __builtin_bit_cast(half2v, rwv);
            a0 = fmaf(w, (float)h[0], a0);
            a1 = fmaf(w, (float)h[1], a1);
        }
        if (vent < NUMENT) {
            float* op = out + (size_t)vent * 128 + loff;
            float2 sp = *reinterpret_cast<const float2*>(op);  // spill contrib (normally 0)
            float2 o;
            o.x = fmaxf(a0 + sp.x, 0.f);
            o.y = fmaxf(a1 + sp.y, 0.f);
            *reinterpret_cast<float2*>(op) = o;
        }
    }
}

// ---------------------------------------------------------------------------
// Fallback path (ws too small / shape out of range): direct vector scatter.
// ---------------------------------------------------------------------------
__global__ void rwb_f32_kernel(const float* __restrict__ rel, const float* __restrict__ W,
                               const float* __restrict__ b, float* __restrict__ rwb, int R) {
    const int k = blockIdx.x;
    const int n = threadIdx.x;
    __shared__ float relk[128];
    relk[n] = rel[(size_t)k * 128 + n];
    __syncthreads();
    const float4* w4 = reinterpret_cast<const float4*>(W + (size_t)n * 128);
    const float4* r4 = reinterpret_cast<const float4*>(relk);
    float acc = 0.f;
#pragma unroll
    for (int i = 0; i < 32; ++i) {
        float4 a = r4[i], w = w4[i];
        acc += a.x * w.x + a.y * w.y + a.z * w.z + a.w * w.w;
    }
    rwb[(size_t)k * 128 + n] = acc + b[n];
}

__global__ void scatter_vec_kernel(const int* __restrict__ heads, const int* __restrict__ tails,
                                   const int* __restrict__ rels, const float* __restrict__ val,
                                   const float* __restrict__ rwb, float* __restrict__ out,
                                   long long nitems) {
    const long long i = (long long)blockIdx.x * blockDim.x + threadIdx.x;
    if (i >= nitems) return;
    const int e = (int)(i >> 5);
    const int c = (int)(i & 31) * 4;
    const float v = val[e];
    float4 rw = *reinterpret_cast<const float4*>(rwb + (size_t)rels[e] * 128 + c);
    float* pt = out + (size_t)tails[e] * 128 + c;
    float* ph = out + (size_t)heads[e] * 128 + c;
    unsafeAtomicAdd(pt + 0, v * rw.x); unsafeAtomicAdd(pt + 1, v * rw.y);
    unsafeAtomicAdd(pt + 2, v * rw.z); unsafeAtomicAdd(pt + 3, v * rw.w);
    unsafeAtomicAdd(ph + 0, v * rw.x); unsafeAtomicAdd(ph + 1, v * rw.y);
    unsafeAtomicAdd(ph + 2, v * rw.z); unsafeAtomicAdd(ph + 3, v * rw.w);
}

__global__ void relu_kernel(float* __restrict__ out, int n4) {
    const int i = blockIdx.x * blockDim.x + threadIdx.x;
    if (i >= n4) return;
    float4* p = reinterpret_cast<float4*>(out) + i;
    float4 v = *p;
    v.x = fmaxf(v.x, 0.f); v.y = fmaxf(v.y, 0.f);
    v.z = fmaxf(v.z, 0.f); v.w = fmaxf(v.w, 0.f);
    *p = v;
}

// ---------------------------------------------------------------------------
extern "C" void kernel_launch(void* const* d_in, const int* in_sizes, int n_in,
                              void* d_out, int out_size, void* d_ws, size_t ws_size,
                              hipStream_t stream) {
    // inputs: 0 local_entity [B*M] (shape only), 1 heads [E], 2 tails [E],
    //         3 rels [E], 4 val [E], 5 rel_features [R*D], 6 W [D*D], 7 b [D]
    const int* heads = (const int*)d_in[1];
    const int* tails = (const int*)d_in[2];
    const int* rels  = (const int*)d_in[3];
    const float* val  = (const float*)d_in[4];
    const float* relf = (const float*)d_in[5];
    const float* W    = (const float*)d_in[6];
    const float* b    = (const float*)d_in[7];
    float* out = (float*)d_out;

    const int NUMENT = in_sizes[0];          // 16000
    const int E      = in_sizes[1];          // 2,000,000
    const int D      = in_sizes[7];          // 128
    const int R      = in_sizes[5] / D;      // 2000

    const int NB = (NUMENT + EPB - 1) / EPB; // 1000 buckets
    // expected endpoints/bucket = 2E*EPB/NUMENT (=4000, sigma~63);
    // slack mean/16+256 ~ +9.6 sigma at default shape
    const long long mean = (2LL * E * EPB) / (NUMENT > 0 ? NUMENT : 1);
    int CAPB = (int)(mean + mean / 16 + 256);

    const size_t rwb_bytes = (size_t)R * D * sizeof(_Float16);          // 512 KB
    const size_t off_gcnt  = (rwb_bytes + 255) & ~(size_t)255;
    const size_t gcnt_b    = (size_t)NB * sizeof(int);
    const size_t off_slots = (off_gcnt + gcnt_b + 255) & ~(size_t)255;
    const size_t slots_b   = (size_t)NB * CAPB * sizeof(unsigned);      // ~18 MB

    if (NB <= MAXNB && R < 4096 && CAPB <= SORTCAP &&
        ws_size >= off_slots + slots_b) {
        _Float16* rwb   = (_Float16*)d_ws;
        int* gcnt       = (int*)((char*)d_ws + off_gcnt);
        unsigned* slots = (unsigned*)((char*)d_ws + off_slots);

        hipMemsetAsync(gcnt, 0, gcnt_b, stream);
        hipMemsetAsync(out, 0, (size_t)out_size * sizeof(float), stream);
        rwb_row_kernel<<<R, 128, 0, stream>>>(relf, W, b, rwb, R);
        bin_kernel<<<(E + FPB - 1) / FPB, 512, 0, stream>>>(
            heads, tails, rels, val, gcnt, slots, rwb, out, E, NB, CAPB);
        gather_kernel<<<NB, 512, 0, stream>>>(slots, gcnt, rwb, out, NUMENT, CAPB);
    } else {
        // fallback: accumulate directly into out (slow but small-ws safe)
        float* rwb = (float*)d_ws;           // R*D fp32 (~1 MB)
        hipMemsetAsync(out, 0, (size_t)out_size * sizeof(float), stream);
        rwb_f32_kernel<<<R, 128, 0, stream>>>(relf, W, b, rwb, R);
        const long long items = (long long)E * 32;
        scatter_vec_kernel<<<(unsigned)((items + 255) / 256), 256, 0, stream>>>(
            heads, tails, rels, val, rwb, out, items);
        relu_kernel<<<(out_size / 4 + 255) / 256, 256, 0, stream>>>(out, out_size / 4);
    }
}

// Round 8
// 196.273 us; speedup vs baseline: 14.1141x; 1.0472x over previous
//
#include <hip/hip_runtime.h>
#include <hip/hip_bf16.h>
#include <cstdint>

typedef _Float16 half2v __attribute__((ext_vector_type(2)));

#define EPB   16        // entities per bucket
#define MAXNB 1024      // max buckets for bin LDS histogram (NUMENT <= 16384)
#define FPB   8192      // facts per bin-block (1024 thr x FPT 8)
#define FPT   8         // facts per thread
#define SORTCAP 4608    // gather LDS payload capacity (u32 -> 18 KB)
#define CPT   9         // ceil(SORTCAP / 512) register-held entries per thread

// payload u32: [31:28]=local entity (4b) | [27:16]=rel (12b, R<4096) | [15:0]=fp16(val)

__device__ __forceinline__ float pay_val(unsigned p) {
    return (float)__builtin_bit_cast(_Float16, (unsigned short)(p & 0xFFFFu));
}

// ---------------------------------------------------------------------------
// Kernel 1: RWB[r][n] = dot(rel_features[r,:], W[n,:]) + b[n]   (fp16, [R][128])
// Also zeroes gcnt and out (fuses the two memset dispatches away: ~55us of the
// round-7 total was inter-dispatch gap; 5 dispatches -> 3).
// ---------------------------------------------------------------------------
__global__ void rwb_row_kernel(const float* __restrict__ rel, const float* __restrict__ W,
                               const float* __restrict__ b, _Float16* __restrict__ rwb,
                               int R, int* __restrict__ gcnt, float* __restrict__ out,
                               int NB, int NUMENT) {
    const int k = blockIdx.x;        // relation index
    const int n = threadIdx.x;       // output feature (0..127)
    // fused zeroing (grid-strided)
    const int gtid = k * 128 + n;
    const int gstr = gridDim.x * 128;
    for (int i = gtid; i < NB; i += gstr) gcnt[i] = 0;
    const int n4 = NUMENT * 32;      // float4 count of out
    const float4 z = {0.f, 0.f, 0.f, 0.f};
    for (int i = gtid; i < n4; i += gstr)
        reinterpret_cast<float4*>(out)[i] = z;

    __shared__ float relk[128];
    relk[n] = rel[(size_t)k * 128 + n];
    __syncthreads();
    const float4* w4 = reinterpret_cast<const float4*>(W + (size_t)n * 128);
    const float4* r4 = reinterpret_cast<const float4*>(relk);
    float acc = 0.f;
#pragma unroll
    for (int i = 0; i < 32; ++i) {
        float4 a = r4[i], w = w4[i];
        acc += a.x * w.x + a.y * w.y + a.z * w.z + a.w * w.w;
    }
    rwb[(size_t)k * 128 + n] = (_Float16)(acc + b[n]);
}

// ---------------------------------------------------------------------------
// Spill path for bucket-capacity overflow (CAPB ~ mean + >9 sigma; guard only).
// ---------------------------------------------------------------------------
__device__ __noinline__ void spill_add(float* __restrict__ out, const _Float16* __restrict__ rwb,
                                       int v, unsigned pay) {
    const int r = (int)((pay >> 16) & 0xFFFu);
    const float val = pay_val(pay);
    float* o = out + (size_t)v * 128;
    const _Float16* rw = rwb + (size_t)r * 128;
    for (int n = 0; n < 128; ++n) unsafeAtomicAdd(o + n, val * (float)rw[n]);
}

// ---------------------------------------------------------------------------
// Kernel 2: bin endpoints into per-bucket lists (bucket = entity >> 4).
// 1024 thr x FPT8 (grid 245 blocks was 1 block/CU at 512thr -> 25% occupancy
// ceiling, latency-bound per round-5 PMC). Same FPB -> same run lengths ->
// same (good) write-amplification profile as round 6.
// ---------------------------------------------------------------------------
__global__ __launch_bounds__(1024) void bin_kernel(
    const int* __restrict__ heads, const int* __restrict__ tails,
    const int* __restrict__ rels, const float* __restrict__ val,
    int* __restrict__ gcnt, unsigned* __restrict__ slots,
    const _Float16* __restrict__ rwb, float* __restrict__ out,
    int E, int NB, int CAPB) {
    __shared__ int cnt[MAXNB];
    __shared__ int gbase[MAXNB];
    const int t = threadIdx.x;
    for (int k = t; k < NB; k += 1024) cnt[k] = 0;
    __syncthreads();

    const int base = blockIdx.x * FPB;
    unsigned payT[FPT], payH[FPT], prT[FPT], prH[FPT];
#pragma unroll
    for (int u = 0; u < FPT; ++u) {
        const int i = base + u * 1024 + t;
        prT[u] = 0xFFFFFFFFu;
        prH[u] = 0xFFFFFFFFu;
        if (i < E) {
            const int tl = tails[i], hd = heads[i], r = rels[i];
            const unsigned hv =
                (unsigned)__builtin_bit_cast(unsigned short, (_Float16)val[i]);
            const int bt = tl >> 4, bh = hd >> 4;            // EPB = 16
            payT[u] = ((unsigned)(tl & 15) << 28) | ((unsigned)r << 16) | hv;
            payH[u] = ((unsigned)(hd & 15) << 28) | ((unsigned)r << 16) | hv;
            const int rt = atomicAdd(&cnt[bt], 1);           // LDS int rank (native)
            const int rh = atomicAdd(&cnt[bh], 1);
            prT[u] = ((unsigned)bt << 16) | (unsigned)rt;    // rank < 16384 fits
            prH[u] = ((unsigned)bh << 16) | (unsigned)rh;
        }
    }
    __syncthreads();
    for (int k = t; k < NB; k += 1024) {
        const int c = cnt[k];
        gbase[k] = c ? atomicAdd(&gcnt[k], c) : 0;           // 1 atomic / bucket / block
    }
    __syncthreads();
#pragma unroll
    for (int u = 0; u < FPT; ++u) {
        if (prT[u] != 0xFFFFFFFFu) {
            {
                const int b1 = (int)(prT[u] >> 16);
                const int pos = gbase[b1] + (int)(prT[u] & 0xFFFFu);
                if (pos < CAPB) slots[(size_t)b1 * CAPB + pos] = payT[u];
                else spill_add(out, rwb, (b1 << 4) | (int)(payT[u] >> 28), payT[u]);
            }
            {
                const int b1 = (int)(prH[u] >> 16);
                const int pos = gbase[b1] + (int)(prH[u] & 0xFFFFu);
                if (pos < CAPB) slots[(size_t)b1 * CAPB + pos] = payH[u];
                else spill_add(out, rwb, (b1 << 4) | (int)(payH[u] >> 28), payH[u]);
            }
        }
    }
}

// ---------------------------------------------------------------------------
// Kernel 3: one 512-thread block per 16-entity bucket.
// Phase A unchanged. Phase B hot loop is now 3 VALU/entry:
//   readfirstlane + 2x v_fma_mix_f32 (inline asm — fp16 val read straight
//   from the SGPR payload lo half, fp16 table element from VGPR lo/hi half;
//   no f16->f32 cvts, no separate mul). Round-7 PMC: 62% VALUBusy ~ 27
//   cy/entry — the compiler wasn't emitting mix ops.
// ---------------------------------------------------------------------------
__global__ __launch_bounds__(512) void gather_kernel(
    const unsigned* __restrict__ slots, const int* __restrict__ gcnt,
    const _Float16* __restrict__ rwb, float* __restrict__ out,
    int NUMENT, int CAPB) {
    __shared__ unsigned se[SORTCAP];           // 18 KB sorted payloads
    __shared__ int cnt[EPB], basep[EPB];
    const int t = threadIdx.x;
    const int b = blockIdx.x;
    if (t < EPB) cnt[t] = 0;
    __syncthreads();

    int deg = gcnt[b];
    if (deg > CAPB) deg = CAPB;        // overflow entries were spilled by bin
    const unsigned* sl = slots + (size_t)b * CAPB;

    // Phase A: coalesced load, LDS rank, hold in registers, sorted placement
    unsigned e[CPT];
    int rk[CPT];
#pragma unroll
    for (int u = 0; u < CPT; ++u) {
        const int k = t + u * 512;
        rk[u] = -1;
        if (k < deg) {
            e[u] = sl[k];
            rk[u] = atomicAdd(&cnt[(int)(e[u] >> 28)], 1);
        }
    }
    __syncthreads();
    if (t == 0) {
        int s = 0;
#pragma unroll
        for (int i = 0; i < EPB; ++i) { basep[i] = s; s += cnt[i]; }
    }
    __syncthreads();
#pragma unroll
    for (int u = 0; u < CPT; ++u)
        if (rk[u] >= 0) se[basep[(int)(e[u] >> 28)] + rk[u]] = e[u];
    __syncthreads();

    // Phase B: 8 waves x 2 entities
    const int wv = t >> 6, lane = t & 63;
    const int loff = lane * 2;                 // _Float16 element offset in row
#pragma unroll
    for (int ei = 0; ei < 2; ++ei) {
        const int le = wv * 2 + ei;
        const int vent = b * EPB + le;
        const int s0 = basep[le], c = cnt[le];
        float a0 = 0.f, a1 = 0.f;
        int j = 0;
        for (; j + 8 <= c; j += 8) {
            unsigned q[8];
#pragma unroll
            for (int u = 0; u < 8; ++u) q[u] = se[s0 + j + u];   // ds_read_b32 broadcast
            unsigned qs[8];
#pragma unroll
            for (int u = 0; u < 8; ++u) qs[u] = __builtin_amdgcn_readfirstlane(q[u]);
            unsigned rw[8];
#pragma unroll
            for (int u = 0; u < 8; ++u) {
                const _Float16* rowp = rwb + (size_t)((qs[u] >> 16) & 0xFFFu) * 128;
                rw[u] = *reinterpret_cast<const unsigned*>(rowp + loff);  // saddr + v_lane
            }
#pragma unroll
            for (int u = 0; u < 8; ++u) {
                // a0 += f16(qs.lo) * f16(rw.lo); a1 += f16(qs.lo) * f16(rw.hi)
                asm("v_fma_mix_f32 %[d], %[s0], %[s1], %[d] op_sel:[0,0,0] op_sel_hi:[1,1,0]"
                    : [d]"+v"(a0) : [s0]"s"(qs[u]), [s1]"v"(rw[u]));
                asm("v_fma_mix_f32 %[d], %[s0], %[s1], %[d] op_sel:[0,1,0] op_sel_hi:[1,1,0]"
                    : [d]"+v"(a1) : [s0]"s"(qs[u]), [s1]"v"(rw[u]));
            }
        }
        for (; j < c; ++j) {
            const unsigned q = se[s0 + j];
            const unsigned qs = __builtin_amdgcn_readfirstlane(q);
            const _Float16* rowp = rwb + (size_t)((qs >> 16) & 0xFFFu) * 128;
            const unsigned rwv = *reinterpret_cast<const unsigned*>(rowp + loff);
            asm("v_fma_mix_f32 %[d], %[s0], %[s1], %[d] op_sel:[0,0,0] op_sel_hi:[1,1,0]"
                : [d]"+v"(a0) : [s0]"s"(qs), [s1]"v"(rwv));
            asm("v_fma_mix_f32 %[d], %[s0], %[s1], %[d] op_sel:[0,1,0] op_sel_hi:[1,1,0]"
                : [d]"+v"(a1) : [s0]"s"(qs), [s1]"v"(rwv));
        }
        if (vent < NUMENT) {
            float* op = out + (size_t)vent * 128 + loff;
            float2 sp = *reinterpret_cast<const float2*>(op);  // spill contrib (normally 0)
            float2 o;
            o.x = fmaxf(a0 + sp.x, 0.f);
            o.y = fmaxf(a1 + sp.y, 0.f);
            *reinterpret_cast<float2*>(op) = o;
        }
    }
}

// ---------------------------------------------------------------------------
// Fallback path (ws too small / shape out of range): direct vector scatter.
// ---------------------------------------------------------------------------
__global__ void rwb_f32_kernel(const float* __restrict__ rel, const float* __restrict__ W,
                               const float* __restrict__ b, float* __restrict__ rwb, int R) {
    const int k = blockIdx.x;
    const int n = threadIdx.x;
    __shared__ float relk[128];
    relk[n] = rel[(size_t)k * 128 + n];
    __syncthreads();
    const float4* w4 = reinterpret_cast<const float4*>(W + (size_t)n * 128);
    const float4* r4 = reinterpret_cast<const float4*>(relk);
    float acc = 0.f;
#pragma unroll
    for (int i = 0; i < 32; ++i) {
        float4 a = r4[i], w = w4[i];
        acc += a.x * w.x + a.y * w.y + a.z * w.z + a.w * w.w;
    }
    rwb[(size_t)k * 128 + n] = acc + b[n];
}

__global__ void scatter_vec_kernel(const int* __restrict__ heads, const int* __restrict__ tails,
                                   const int* __restrict__ rels, const float* __restrict__ val,
                                   const float* __restrict__ rwb, float* __restrict__ out,
                                   long long nitems) {
    const long long i = (long long)blockIdx.x * blockDim.x + threadIdx.x;
    if (i >= nitems) return;
    const int e = (int)(i >> 5);
    const int c = (int)(i & 31) * 4;
    const float v = val[e];
    float4 rw = *reinterpret_cast<const float4*>(rwb + (size_t)rels[e] * 128 + c);
    float* pt = out + (size_t)tails[e] * 128 + c;
    float* ph = out + (size_t)heads[e] * 128 + c;
    unsafeAtomicAdd(pt + 0, v * rw.x); unsafeAtomicAdd(pt + 1, v * rw.y);
    unsafeAtomicAdd(pt + 2, v * rw.z); unsafeAtomicAdd(pt + 3, v * rw.w);
    unsafeAtomicAdd(ph + 0, v * rw.x); unsafeAtomicAdd(ph + 1, v * rw.y);
    unsafeAtomicAdd(ph + 2, v * rw.z); unsafeAtomicAdd(ph + 3, v * rw.w);
}

__global__ void relu_kernel(float* __restrict__ out, int n4) {
    const int i = blockIdx.x * blockDim.x + threadIdx.x;
    if (i >= n4) return;
    float4* p = reinterpret_cast<float4*>(out) + i;
    float4 v = *p;
    v.x = fmaxf(v.x, 0.f); v.y = fmaxf(v.y, 0.f);
    v.z = fmaxf(v.z, 0.f); v.w = fmaxf(v.w, 0.f);
    *p = v;
}

// ---------------------------------------------------------------------------
extern "C" void kernel_launch(void* const* d_in, const int* in_sizes, int n_in,
                              void* d_out, int out_size, void* d_ws, size_t ws_size,
                              hipStream_t stream) {
    // inputs: 0 local_entity [B*M] (shape only), 1 heads [E], 2 tails [E],
    //         3 rels [E], 4 val [E], 5 rel_features [R*D], 6 W [D*D], 7 b [D]
    const int* heads = (const int*)d_in[1];
    const int* tails = (const int*)d_in[2];
    const int* rels  = (const int*)d_in[3];
    const float* val  = (const float*)d_in[4];
    const float* relf = (const float*)d_in[5];
    const float* W    = (const float*)d_in[6];
    const float* b    = (const float*)d_in[7];
    float* out = (float*)d_out;

    const int NUMENT = in_sizes[0];          // 16000
    const int E      = in_sizes[1];          // 2,000,000
    const int D      = in_sizes[7];          // 128
    const int R      = in_sizes[5] / D;      // 2000

    const int NB = (NUMENT + EPB - 1) / EPB; // 1000 buckets
    // expected endpoints/bucket = 2E*EPB/NUMENT (=4000, sigma~63);
    // slack mean/16+256 ~ +9.6 sigma at default shape
    const long long mean = (2LL * E * EPB) / (NUMENT > 0 ? NUMENT : 1);
    int CAPB = (int)(mean + mean / 16 + 256);

    const size_t rwb_bytes = (size_t)R * D * sizeof(_Float16);          // 512 KB
    const size_t off_gcnt  = (rwb_bytes + 255) & ~(size_t)255;
    const size_t gcnt_b    = (size_t)NB * sizeof(int);
    const size_t off_slots = (off_gcnt + gcnt_b + 255) & ~(size_t)255;
    const size_t slots_b   = (size_t)NB * CAPB * sizeof(unsigned);      // ~18 MB

    if (NB <= MAXNB && R < 4096 && CAPB <= SORTCAP &&
        ws_size >= off_slots + slots_b) {
        _Float16* rwb   = (_Float16*)d_ws;
        int* gcnt       = (int*)((char*)d_ws + off_gcnt);
        unsigned* slots = (unsigned*)((char*)d_ws + off_slots);

        rwb_row_kernel<<<R, 128, 0, stream>>>(relf, W, b, rwb, R, gcnt, out, NB, NUMENT);
        bin_kernel<<<(E + FPB - 1) / FPB, 1024, 0, stream>>>(
            heads, tails, rels, val, gcnt, slots, rwb, out, E, NB, CAPB);
        gather_kernel<<<NB, 512, 0, stream>>>(slots, gcnt, rwb, out, NUMENT, CAPB);
    } else {
        // fallback: accumulate directly into out (slow but small-ws safe)
        float* rwb = (float*)d_ws;           // R*D fp32 (~1 MB)
        hipMemsetAsync(out, 0, (size_t)out_size * sizeof(float), stream);
        rwb_f32_kernel<<<R, 128, 0, stream>>>(relf, W, b, rwb, R);
        const long long items = (long long)E * 32;
        scatter_vec_kernel<<<(unsigned)((items + 255) / 256), 256, 0, stream>>>(
            heads, tails, rels, val, rwb, out, items);
        relu_kernel<<<(out_size / 4 + 255) / 256, 256, 0, stream>>>(out, out_size / 4);
    }
}